// Round 1
// baseline (6651.259 us; speedup 1.0000x reference)
//
#include <hip/hip_runtime.h>
#include <hip/hip_bf16.h>
#include <math.h>

// ---------------------------------------------------------------------------
// MaskedViT forward. R5: same as verified R4 (11011 us) except gemm_bf16
// staging switched from reg-staged int4 global->LDS to
// __builtin_amdgcn_global_load_lds width=16 (ladder step-3 lever, m193 +67%).
// Inputs fp32, output fp32. Internal: bf16 MFMA GEMMs, fp32 residual master,
// fp32 gate path (top-k rank safety).
// ---------------------------------------------------------------------------

typedef __bf16 bf16_t;
typedef __attribute__((ext_vector_type(8))) __bf16 bf16x8;
typedef __attribute__((ext_vector_type(4))) float f32x4;

#define DI __device__ __forceinline__

constexpr int NB     = 32;
constexpr int NTOK   = 197;
constexpr int DMODEL = 768;
constexpr int NHEAD  = 12;
constexpr int HDIM   = 64;
constexpr int HIDN   = 3072;
constexpr int GHID   = 128;
constexpr int MROWS  = NB * NTOK;   // 6304
constexpr int PROWS  = NB * 196;    // 6272
constexpr int NLAYER = 12;          // 2 warm + 10 dyn
constexpr int KTOP   = 118;
constexpr float ATT_SCALE = 0.125f;           // HD^-0.5
constexpr float LNEPS  = 1e-5f;
constexpr float LOGEPS = -13.815510558f;      // log(1e-6)

DI f32x4 mfma16(bf16x8 a, bf16x8 b, f32x4 c) {
    return __builtin_amdgcn_mfma_f32_16x16x32_bf16(a, b, c, 0, 0, 0);
}

// async global->LDS, 16B per lane. LDS dest must be wave-uniform base;
// HW writes lane's 16B at base + lane*16.
DI void gld_lds16(const void* g, void* l) {
    __builtin_amdgcn_global_load_lds(
        (__attribute__((address_space(1))) void*)(g),
        (__attribute__((address_space(3))) void*)(l), 16, 0, 0);
}

// ------------------------------- GEMM --------------------------------------
// C[M,N] = epilogue(A[M,K] @ Wt[N,K]^T + bias[N]); A,Wt bf16, acc fp32.
// 128x128 tile, BK=32, 4 waves in 2x2, each wave 64x64 (4x4 MFMA frags).
// Staging via global_load_lds width=16: LDS layout is linear in
// s = tid + i*256 order (byte offset s*16), matching wave-uniform-base +
// lane*16. OOB rows are CLAMPED (valid reads; results discarded in epilogue).
enum { EP_BF16 = 0, EP_GELU = 1, EP_RES = 2, EP_RESMASK = 3, EP_F32 = 4 };

template<int MODE>
__global__ __launch_bounds__(256)
void gemm_bf16(const bf16_t* __restrict__ A, const bf16_t* __restrict__ Wt,
               const float* __restrict__ bias, void* __restrict__ Cout,
               float* __restrict__ resid, const float* __restrict__ rowmask,
               int M, int N, int K, int ldc)
{
    __shared__ __align__(16) bf16_t As[128 * 32];
    __shared__ __align__(16) bf16_t Bs[128 * 32];
    const int tid  = threadIdx.x;
    const int lane = tid & 63;
    const int wave = tid >> 6;
    const int wm = wave >> 1, wn = wave & 1;
    const int quad = lane >> 4, l16 = lane & 15;
    const int m0 = blockIdx.y * 128;
    const int n0 = blockIdx.x * 128;

    f32x4 zero4 = {0.f, 0.f, 0.f, 0.f};
    f32x4 acc[4][4];
#pragma unroll
    for (int i = 0; i < 4; ++i)
#pragma unroll
        for (int j = 0; j < 4; ++j) acc[i][j] = zero4;

    // per-lane global source rows (clamped to valid memory) and
    // wave-uniform LDS destinations for the two 64-row half-tiles.
    const int rh  = tid >> 2;              // 0..63
    const int seg = tid & 3;               // 0..3 (8 bf16 each)
    const int rA0 = min(m0 + rh,      M - 1);
    const int rA1 = min(m0 + 64 + rh, M - 1);
    const int rB0 = min(n0 + rh,      N - 1);
    const int rB1 = min(n0 + 64 + rh, N - 1);
    const bf16_t* pA0 = A  + (size_t)rA0 * K + seg * 8;
    const bf16_t* pA1 = A  + (size_t)rA1 * K + seg * 8;
    const bf16_t* pB0 = Wt + (size_t)rB0 * K + seg * 8;
    const bf16_t* pB1 = Wt + (size_t)rB1 * K + seg * 8;
    bf16_t* lA0 = As + wave * 512;          // (wave*64 + 0*256)*8
    bf16_t* lA1 = As + 2048 + wave * 512;   // (wave*64 + 1*256)*8
    bf16_t* lB0 = Bs + wave * 512;
    bf16_t* lB1 = Bs + 2048 + wave * 512;

    const int nkt = K >> 5;
    for (int kt = 0; kt < nkt; ++kt) {
        const int kb = kt << 5;
        __syncthreads();   // previous iter's ds_reads done before overwrite
        gld_lds16(pA0 + kb, lA0);
        gld_lds16(pA1 + kb, lA1);
        gld_lds16(pB0 + kb, lB0);
        gld_lds16(pB1 + kb, lB1);
        __syncthreads();   // barrier drains vmcnt -> tile visible

        bf16x8 af[4], bfr[4];
#pragma unroll
        for (int i = 0; i < 4; ++i)
            af[i] = *reinterpret_cast<const bf16x8*>(As + (wm * 64 + i * 16 + l16) * 32 + quad * 8);
#pragma unroll
        for (int j = 0; j < 4; ++j)
            bfr[j] = *reinterpret_cast<const bf16x8*>(Bs + (wn * 64 + j * 16 + l16) * 32 + quad * 8);
#pragma unroll
        for (int i = 0; i < 4; ++i)
#pragma unroll
            for (int j = 0; j < 4; ++j)
                acc[i][j] = mfma16(af[i], bfr[j], acc[i][j]);
    }

    // epilogue: C/D layout col=lane&15, row=quad*4+reg
#pragma unroll
    for (int j = 0; j < 4; ++j) {
        int c = n0 + wn * 64 + j * 16 + l16;
        if (c >= N) continue;
        float bj = bias ? bias[c] : 0.f;
#pragma unroll
        for (int i = 0; i < 4; ++i) {
#pragma unroll
            for (int r = 0; r < 4; ++r) {
                int mr = m0 + wm * 64 + i * 16 + quad * 4 + r;
                if (mr >= M) continue;
                float v = acc[i][j][r] + bj;
                size_t off = (size_t)mr * ldc + c;
                if (MODE == EP_BF16) {
                    ((bf16_t*)Cout)[off] = (bf16_t)v;
                } else if (MODE == EP_GELU) {
                    float g = 0.5f * v * (1.f + erff(v * 0.70710678118f));
                    ((bf16_t*)Cout)[off] = (bf16_t)g;
                } else if (MODE == EP_F32) {
                    ((float*)Cout)[off] = v;
                } else if (MODE == EP_RES) {
                    resid[off] += v;
                } else { // EP_RESMASK
                    resid[off] += v * rowmask[mr];
                }
            }
        }
    }
}

// ------------------------------ LayerNorm ----------------------------------
DI float block_reduce_sum(float val, float* sh) {
#pragma unroll
    for (int off = 32; off; off >>= 1) val += __shfl_down(val, off, 64);
    __syncthreads();
    if ((threadIdx.x & 63) == 0) sh[threadIdx.x >> 6] = val;
    __syncthreads();
    return sh[0] + sh[1] + sh[2] + sh[3];
}

// in row = blockIdx.x * row_mul (fp32); OUT = bf16 or fp32
template<typename OUT>
__global__ __launch_bounds__(256)
void ln_kernel(const float* __restrict__ X, const float* __restrict__ g,
               const float* __restrict__ bta, OUT* __restrict__ H, int row_mul)
{
    __shared__ float sh[4];
    const int t = threadIdx.x;
    const float* xr = X + (size_t)blockIdx.x * row_mul * DMODEL;
    float v[3];
#pragma unroll
    for (int i = 0; i < 3; ++i) v[i] = xr[t + i * 256];
    float s = v[0] + v[1] + v[2];
    s = block_reduce_sum(s, sh);
    float mu = s * (1.f / DMODEL);
    float q = 0.f;
#pragma unroll
    for (int i = 0; i < 3; ++i) { float d = v[i] - mu; q += d * d; }
    q = block_reduce_sum(q, sh);
    float rstd = rsqrtf(q * (1.f / DMODEL) + LNEPS);
    OUT* hr = H + (size_t)blockIdx.x * DMODEL;
#pragma unroll
    for (int i = 0; i < 3; ++i) {
        int c = t + i * 256;
        hr[c] = (OUT)((v[i] - mu) * rstd * g[c] + bta[c]);
    }
}

// ------------------------------ Attention ----------------------------------
// Block = (qtile of 64 queries) x head x batch; 4 waves, wave = 16 queries.
// QK^T and PV via 16x16x32 MFMA; V^T staged in LDS; P routed via LDS.
__global__ __launch_bounds__(256)
void attn_kernel(const bf16_t* __restrict__ qkv,   // [B][197][3][768]
                 const float* __restrict__ addmask, // [B][197] or null
                 bf16_t* __restrict__ outp)          // [B][197][768]
{
    constexpr int KP = 232;  // padded key stride (>=224, 16B-multiple rows)
    __shared__ __align__(16) bf16_t Vt[64 * KP];       // Vt[hd][key]
    __shared__ __align__(16) bf16_t Ps[4][16 * KP];    // per-wave P[q][key]
    const int b = blockIdx.z, h = blockIdx.y, qt = blockIdx.x;
    const int tid = threadIdx.x, wave = tid >> 6, lane = tid & 63;
    const int quad = lane >> 4, l16 = lane & 15;

    // stage V^T (zero-padded keys 197..223)
    {
        int d = tid & 63, ng = tid >> 6;
        for (int n = ng; n < 224; n += 4) {
            bf16_t v = (bf16_t)0.f;
            if (n < 197)
                v = qkv[(((size_t)b * NTOK + n) * 3 + 2) * DMODEL + h * HDIM + d];
            Vt[d * KP + n] = v;
        }
    }
    __syncthreads();

    // Q fragments straight from global (A-op: m=lane&15, k=quad*8+j)
    const int qbase = qt * 64 + wave * 16;
    const int qrow = qbase + l16;
    const int qc = qrow < 196 ? qrow : 196;
    bf16x8 aq[2];
#pragma unroll
    for (int t = 0; t < 2; ++t)
        aq[t] = *reinterpret_cast<const bf16x8*>(
            qkv + (((size_t)b * NTOK + qc) * 3 + 0) * DMODEL + h * HDIM + t * 32 + quad * 8);

    // scores: 13 key-tiles of 16
    float sreg[13][4];
#pragma unroll
    for (int kt = 0; kt < 13; ++kt) {
        int key = kt * 16 + l16;
        int kc = key < 196 ? key : 196;
        const bf16_t* kb = qkv + (((size_t)b * NTOK + kc) * 3 + 1) * DMODEL + h * HDIM;
        bf16x8 kf0 = *reinterpret_cast<const bf16x8*>(kb + quad * 8);
        bf16x8 kf1 = *reinterpret_cast<const bf16x8*>(kb + 32 + quad * 8);
        f32x4 s = {0.f, 0.f, 0.f, 0.f};
        s = mfma16(aq[0], kf0, s);
        s = mfma16(aq[1], kf1, s);
        float am = addmask ? addmask[b * NTOK + kc] : 0.f;
        bool kvalid = key < 197;
#pragma unroll
        for (int r = 0; r < 4; ++r)
            sreg[kt][r] = kvalid ? (s[r] * ATT_SCALE + am) : -1e30f;
    }

    // softmax rows (row = quad*4+r, spread over the 16 lanes of the quad)
    float psum[4];
#pragma unroll
    for (int r = 0; r < 4; ++r) {
        float mx = -1e30f;
#pragma unroll
        for (int kt = 0; kt < 13; ++kt) mx = fmaxf(mx, sreg[kt][r]);
#pragma unroll
        for (int d = 1; d < 16; d <<= 1) mx = fmaxf(mx, __shfl_xor(mx, d, 64));
        float sum = 0.f;
#pragma unroll
        for (int kt = 0; kt < 13; ++kt) {
            float p = expf(sreg[kt][r] - mx);
            sreg[kt][r] = p;
            sum += p;
        }
#pragma unroll
        for (int d = 1; d < 16; d <<= 1) sum += __shfl_xor(sum, d, 64);
        psum[r] = sum;
    }

    // write P to LDS (C-layout -> A-layout transform), zero-pad cols 208..223
#pragma unroll
    for (int kt = 0; kt < 13; ++kt)
#pragma unroll
        for (int r = 0; r < 4; ++r)
            Ps[wave][(quad * 4 + r) * KP + kt * 16 + l16] = (bf16_t)sreg[kt][r];
    {
        int rr = lane & 15, c0 = 208 + (lane >> 4) * 4;
#pragma unroll
        for (int i = 0; i < 4; ++i) Ps[wave][rr * KP + c0 + i] = (bf16_t)0.f;
    }
    __syncthreads();   // P-write -> PV-read ordering

    // O = P @ V  (7 K-steps of 32 keys)
    f32x4 o[4];
#pragma unroll
    for (int j = 0; j < 4; ++j) o[j] = (f32x4){0.f, 0.f, 0.f, 0.f};
#pragma unroll
    for (int ks = 0; ks < 7; ++ks) {
        bf16x8 ap = *reinterpret_cast<const bf16x8*>(&Ps[wave][l16 * KP + ks * 32 + quad * 8]);
#pragma unroll
        for (int j = 0; j < 4; ++j) {
            bf16x8 vf = *reinterpret_cast<const bf16x8*>(&Vt[(j * 16 + l16) * KP + ks * 32 + quad * 8]);
            o[j] = mfma16(ap, vf, o[j]);
        }
    }

    // normalize + store
#pragma unroll
    for (int r = 0; r < 4; ++r) {
        int q = qbase + quad * 4 + r;
        if (q < 197) {
            float rs = 1.f / fmaxf(psum[r], 1e-20f);
#pragma unroll
            for (int j = 0; j < 4; ++j)
                outp[((size_t)b * NTOK + q) * DMODEL + h * HDIM + j * 16 + l16] =
                    (bf16_t)(o[j][r] * rs);
        }
    }
}

// --------------------------- small kernels ---------------------------------
// dst[n][k] = (bf16)src[k][n], src fp32; per-layer blockIdx.z
__global__ __launch_bounds__(256)
void transpose_f32(const float* __restrict__ src, bf16_t* __restrict__ dst, int K, int N)
{
    __shared__ bf16_t tile[64][65];
    const size_t ls = (size_t)K * N * blockIdx.z;
    int k0 = blockIdx.y * 64, n0 = blockIdx.x * 64;
    int c = threadIdx.x & 63, r0 = threadIdx.x >> 6;
#pragma unroll
    for (int i = 0; i < 16; ++i) {
        int r = r0 + i * 4;
        tile[r][c] = (k0 + r < K && n0 + c < N)
                   ? (bf16_t)src[ls + (size_t)(k0 + r) * N + n0 + c] : (bf16_t)0.f;
    }
    __syncthreads();
#pragma unroll
    for (int i = 0; i < 16; ++i) {
        int r = r0 + i * 4;  // n-dim
        if (n0 + r < N && k0 + c < K) dst[ls + (size_t)(n0 + r) * K + k0 + c] = tile[c][r];
    }
}

__global__ void cvt_f32_bf16(const float* __restrict__ src, bf16_t* __restrict__ dst, int n)
{
    int i = blockIdx.x * 256 + threadIdx.x;
    if (i < n) dst[i] = (bf16_t)src[i];
}

__global__ void im2col_kernel(const float* __restrict__ img, bf16_t* __restrict__ Ap)
{
    int idx = blockIdx.x * 256 + threadIdx.x;
    if (idx >= PROWS * 768) return;
    int col = idx % 768, row = idx / 768;
    int b = row / 196, t = row % 196;
    int gi = t / 14, gj = t % 14;
    int c = col >> 8, rr = col & 255, p = rr >> 4, q = rr & 15;
    Ap[idx] = (bf16_t)img[(((size_t)b * 3 + c) * 224 + gi * 16 + p) * 224 + gj * 16 + q];
}

__global__ void assemble_x(const float* __restrict__ patch, const float* __restrict__ cls,
                           const float* __restrict__ pos, float* __restrict__ X)
{
    int idx = blockIdx.x * 256 + threadIdx.x;
    if (idx >= MROWS * DMODEL) return;
    int d = idx % DMODEL, rest = idx / DMODEL;
    int n = rest % NTOK, b = rest / NTOK;
    float v;
    if (n == 0) v = cls[d] + pos[d];
    else        v = patch[((size_t)b * 196 + (n - 1)) * DMODEL + d] + pos[(size_t)n * DMODEL + d];
    X[idx] = v;
}

// ---- gate path (fp32 end-to-end; top-k ranks must match np exactly) -------
// C[M,128] = gelu(A[M,768] @ W[768,128] + b); all fp32 vector math.
__global__ __launch_bounds__(256)
void gate_gemm_f32(const float* __restrict__ A, const float* __restrict__ W,
                   const float* __restrict__ b, float* __restrict__ C, int M)
{
    __shared__ float As[64][33];
    __shared__ float Ws[32][128];
    const int m0 = blockIdx.x * 64;
    const int tx = threadIdx.x & 15, ty = threadIdx.x >> 4;  // 16 x 16
    float acc[4][8] = {};
    for (int k0 = 0; k0 < 768; k0 += 32) {
        __syncthreads();
        for (int i = threadIdx.x; i < 64 * 32; i += 256) {
            int r = i >> 5, c = i & 31;
            int gm = m0 + r;
            As[r][c] = (gm < M) ? A[(size_t)gm * 768 + k0 + c] : 0.f;
        }
        for (int i = threadIdx.x; i < 32 * 128; i += 256) {
            int r = i >> 7, c = i & 127;
            Ws[r][c] = W[(size_t)(k0 + r) * 128 + c];
        }
        __syncthreads();
#pragma unroll
        for (int kk = 0; kk < 32; ++kk) {
            float a[4], w[8];
#pragma unroll
            for (int i = 0; i < 4; ++i) a[i] = As[ty * 4 + i][kk];
#pragma unroll
            for (int j = 0; j < 8; ++j) w[j] = Ws[kk][tx * 8 + j];
#pragma unroll
            for (int i = 0; i < 4; ++i)
#pragma unroll
                for (int j = 0; j < 8; ++j) acc[i][j] += a[i] * w[j];
        }
    }
#pragma unroll
    for (int i = 0; i < 4; ++i) {
        int gm = m0 + ty * 4 + i;
        if (gm >= M) continue;
#pragma unroll
        for (int j = 0; j < 8; ++j) {
            int c = tx * 8 + j;
            float v = acc[i][j] + b[c];
            C[(size_t)gm * GHID + c] = 0.5f * v * (1.f + erff(v * 0.70710678118f));
        }
    }
}

__global__ __launch_bounds__(128)
void gate_dot(const float* __restrict__ ghid, const float* __restrict__ w2,
              const float* __restrict__ b2, float* __restrict__ logits)
{
    __shared__ float sh[2];
    int row = blockIdx.x, t = threadIdx.x;
    float v = ghid[(size_t)row * GHID + t] * w2[t];
#pragma unroll
    for (int off = 32; off; off >>= 1) v += __shfl_down(v, off, 64);
    if ((t & 63) == 0) sh[t >> 6] = v;
    __syncthreads();
    if (t == 0) logits[row] = sh[0] + sh[1] + b2[0];
}

// exact top-118 of logits[b,1:197] by rank counting (lax.top_k tie-break: lower index)
__global__ __launch_bounds__(256)
void topk_kernel(const float* __restrict__ logits, float* __restrict__ maskm,
                 float* __restrict__ addm)
{
    __shared__ float ls[196];
    int b = blockIdx.x, t = threadIdx.x;
    if (t < 196) ls[t] = logits[b * NTOK + 1 + t];
    __syncthreads();
    if (t < 196) {
        float li = ls[t];
        int cnt = 0;
        for (int j = 0; j < 196; ++j) {
            float lj = ls[j];
            cnt += (lj > li) || (lj == li && j < t);
        }
        bool sel = cnt < KTOP;
        maskm[b * NTOK + 1 + t] = sel ? 1.f : 0.f;
        addm[b * NTOK + 1 + t]  = sel ? 0.f : LOGEPS;
    }
    if (t == 0) { maskm[b * NTOK] = 1.f; addm[b * NTOK] = 0.f; }
}

__global__ void fill_sentinel(float* out, int n)
{
    int i = blockIdx.x * 256 + threadIdx.x;
    if (i < n) out[i] = 12345.0f;
}

// ------------------------------- host --------------------------------------
static void launch_gemm(int mode, const bf16_t* A, const bf16_t* Wt, const float* bias,
                        void* C, float* resid, const float* rowmask,
                        int M, int N, int K, int ldc, hipStream_t s)
{
    dim3 grid((N + 127) / 128, (M + 127) / 128);
    dim3 blk(256);
    switch (mode) {
    case EP_BF16:    gemm_bf16<EP_BF16><<<grid, blk, 0, s>>>(A, Wt, bias, C, resid, rowmask, M, N, K, ldc); break;
    case EP_GELU:    gemm_bf16<EP_GELU><<<grid, blk, 0, s>>>(A, Wt, bias, C, resid, rowmask, M, N, K, ldc); break;
    case EP_RES:     gemm_bf16<EP_RES><<<grid, blk, 0, s>>>(A, Wt, bias, C, resid, rowmask, M, N, K, ldc); break;
    case EP_RESMASK: gemm_bf16<EP_RESMASK><<<grid, blk, 0, s>>>(A, Wt, bias, C, resid, rowmask, M, N, K, ldc); break;
    case EP_F32:     gemm_bf16<EP_F32><<<grid, blk, 0, s>>>(A, Wt, bias, C, resid, rowmask, M, N, K, ldc); break;
    }
}

extern "C" void kernel_launch(void* const* d_in, const int* in_sizes, int n_in,
                              void* d_out, int out_size, void* d_ws, size_t ws_size,
                              hipStream_t stream)
{
    (void)in_sizes; (void)n_in;
    const float* images   = (const float*)d_in[0];
    const float* patch_w  = (const float*)d_in[1];
    const float* patch_b  = (const float*)d_in[2];
    const float* cls_tok  = (const float*)d_in[3];
    const float* pos_emb  = (const float*)d_in[4];
    const float* w_ln1_g  = (const float*)d_in[5];
    const float* w_ln1_b  = (const float*)d_in[6];
    const float* w_qkv_w  = (const float*)d_in[7];
    const float* w_qkv_b  = (const float*)d_in[8];
    const float* w_proj_w = (const float*)d_in[9];
    const float* w_proj_b = (const float*)d_in[10];
    const float* w_ln2_g  = (const float*)d_in[11];
    const float* w_ln2_b  = (const float*)d_in[12];
    const float* w_fc1_w  = (const float*)d_in[13];
    const float* w_fc1_b  = (const float*)d_in[14];
    const float* w_fc2_w  = (const float*)d_in[15];
    const float* w_fc2_b  = (const float*)d_in[16];
    const float* d_ln1_g  = (const float*)d_in[17];
    const float* d_ln1_b  = (const float*)d_in[18];
    const float* d_qkv_w  = (const float*)d_in[19];
    const float* d_qkv_b  = (const float*)d_in[20];
    const float* d_proj_w = (const float*)d_in[21];
    const float* d_proj_b = (const float*)d_in[22];
    const float* d_ln2_g  = (const float*)d_in[23];
    const float* d_ln2_b  = (const float*)d_in[24];
    const float* d_fc1_w  = (const float*)d_in[25];
    const float* d_fc1_b  = (const float*)d_in[26];
    const float* d_fc2_w  = (const float*)d_in[27];
    const float* d_fc2_b  = (const float*)d_in[28];
    const float* d_gln_g  = (const float*)d_in[29];
    const float* d_gln_b  = (const float*)d_in[30];
    const float* d_gw1    = (const float*)d_in[31];
    const float* d_gb1    = (const float*)d_in[32];
    const float* d_gw2    = (const float*)d_in[33];
    const float* d_gb2    = (const float*)d_in[34];
    const float* norm_g   = (const float*)d_in[35];
    const float* norm_b   = (const float*)d_in[36];
    const float* head_w   = (const float*)d_in[37];
    const float* head_b   = (const float*)d_in[38];

    // workspace layout
    char* wp = (char*)d_ws;
    auto alloc = [&](size_t bytes) -> char* {
        char* p = wp; wp += (bytes + 255) & ~(size_t)255; return p;
    };
    bf16_t* wtqkv  = (bf16_t*)alloc((size_t)NLAYER * 2304 * 768 * 2);
    bf16_t* wtproj = (bf16_t*)alloc((size_t)NLAYER * 768 * 768 * 2);
    bf16_t* wtfc1  = (bf16_t*)alloc((size_t)NLAYER * 3072 * 768 * 2);
    bf16_t* wtfc2  = (bf16_t*)alloc((size_t)NLAYER * 768 * 3072 * 2);
    bf16_t* wthead = (bf16_t*)alloc((size_t)1024 * 768 * 2);
    bf16_t* pwbf   = (bf16_t*)alloc((size_t)768 * 768 * 2);
    float*  x      = (float*)alloc((size_t)MROWS * DMODEL * 4);
    bf16_t* h      = (bf16_t*)alloc((size_t)MROWS * DMODEL * 2);
    float*  hgate  = (float*)alloc((size_t)MROWS * DMODEL * 4);
    bf16_t* hcls   = (bf16_t*)alloc((size_t)NB * DMODEL * 2);
    bf16_t* qkvb   = (bf16_t*)alloc((size_t)MROWS * 2304 * 2);
    bf16_t* attno  = (bf16_t*)alloc((size_t)MROWS * DMODEL * 2);
    bf16_t* hid    = (bf16_t*)alloc((size_t)MROWS * HIDN * 2);
    float*  ghid   = (float*)alloc((size_t)MROWS * GHID * 4);
    float*  logits = (float*)alloc((size_t)MROWS * 4);
    float*  maskm  = (float*)alloc((size_t)MROWS * 4);
    float*  addm   = (float*)alloc((size_t)MROWS * 4);
    size_t used = (size_t)(wp - (char*)d_ws);
    if (used > ws_size) {  // diagnostic: distinctive absmax if ws is too small
        fill_sentinel<<<(out_size + 255) / 256, 256, 0, stream>>>((float*)d_out, out_size);
        return;
    }
    // patch scratch aliases hid (patch phase precedes any MLP use)
    bf16_t* Ap = hid;                                    // [6272][768] bf16
    float* patchout = (float*)((char*)hid + (size_t)PROWS * 768 * 2); // [6272][768] f32

    // ---- weight pre-transpose ([K][N] -> [N][K] bf16) ----
    transpose_f32<<<dim3(36, 12, 2),  256, 0, stream>>>(w_qkv_w,  wtqkv,                      768, 2304);
    transpose_f32<<<dim3(36, 12, 10), 256, 0, stream>>>(d_qkv_w,  wtqkv + (size_t)2*2304*768, 768, 2304);
    transpose_f32<<<dim3(12, 12, 2),  256, 0, stream>>>(w_proj_w, wtproj,                     768, 768);
    transpose_f32<<<dim3(12, 12, 10), 256, 0, stream>>>(d_proj_w, wtproj + (size_t)2*768*768, 768, 768);
    transpose_f32<<<dim3(48, 12, 2),  256, 0, stream>>>(w_fc1_w,  wtfc1,                      768, 3072);
    transpose_f32<<<dim3(48, 12, 10), 256, 0, stream>>>(d_fc1_w,  wtfc1 + (size_t)2*3072*768, 768, 3072);
    transpose_f32<<<dim3(12, 48, 2),  256, 0, stream>>>(w_fc2_w,  wtfc2,                      3072, 768);
    transpose_f32<<<dim3(12, 48, 10), 256, 0, stream>>>(d_fc2_w,  wtfc2 + (size_t)2*768*3072, 3072, 768);
    transpose_f32<<<dim3(16, 12, 1),  256, 0, stream>>>(head_w,   wthead,                     768, 1000);
    cvt_f32_bf16<<<(768 * 768 + 255) / 256, 256, 0, stream>>>(patch_w, pwbf, 768 * 768);

    // ---- patch embed + assemble ----
    im2col_kernel<<<(PROWS * 768 + 255) / 256, 256, 0, stream>>>(images, Ap);
    // patch_w is [D][C*P*P] = already [N][K]: use bf16 copy directly as Wt
    launch_gemm(EP_F32, Ap, pwbf, patch_b, patchout, nullptr, nullptr,
                PROWS, 768, 768, 768, stream);
    assemble_x<<<(MROWS * DMODEL + 255) / 256, 256, 0, stream>>>(patchout, cls_tok, pos_emb, x);

    // ---- transformer layers ----
    for (int L = 0; L < NLAYER; ++L) {
        bool warm = (L < 2);
        int li = warm ? L : (L - 2);
        const float* ln1g = warm ? w_ln1_g + li*768 : d_ln1_g + li*768;
        const float* ln1b = warm ? w_ln1_b + li*768 : d_ln1_b + li*768;
        const float* ln2g = warm ? w_ln2_g + li*768 : d_ln2_g + li*768;
        const float* ln2b = warm ? w_ln2_b + li*768 : d_ln2_b + li*768;
        const float* qkvbias  = warm ? w_qkv_b + li*2304 : d_qkv_b + li*2304;
        const float* projbias = warm ? w_proj_b + li*768 : d_proj_b + li*768;
        const float* fc1bias  = warm ? w_fc1_b + (size_t)li*3072 : d_fc1_b + (size_t)li*3072;
        const float* fc2bias  = warm ? w_fc2_b + li*768 : d_fc2_b + li*768;
        const bf16_t* Wq = wtqkv + (size_t)L * 2304 * 768;
        const bf16_t* Wp = wtproj + (size_t)L * 768 * 768;
        const bf16_t* W1 = wtfc1 + (size_t)L * 3072 * 768;
        const bf16_t* W2 = wtfc2 + (size_t)L * 768 * 3072;

        if (!warm) {
            // gate: LN -> fc1+gelu -> 128-dot -> top-118 mask   (all fp32)
            ln_kernel<float><<<MROWS, 256, 0, stream>>>(x, d_gln_g + li*768, d_gln_b + li*768, hgate, 1);
            gate_gemm_f32<<<(MROWS + 63) / 64, 256, 0, stream>>>(
                hgate, d_gw1 + (size_t)li*768*128, d_gb1 + li*128, ghid, MROWS);
            gate_dot<<<MROWS, 128, 0, stream>>>(ghid, d_gw2 + (size_t)li*128, d_gb2 + li, logits);
            topk_kernel<<<NB, 256, 0, stream>>>(logits, maskm, addm);
        }
        // attention
        ln_kernel<bf16_t><<<MROWS, 256, 0, stream>>>(x, ln1g, ln1b, h, 1);
        launch_gemm(EP_BF16, h, Wq, qkvbias, qkvb, nullptr, nullptr,
                    MROWS, 2304, 768, 2304, stream);
        attn_kernel<<<dim3(4, NHEAD, NB), 256, 0, stream>>>(qkvb, warm ? nullptr : addm, attno);
        launch_gemm(EP_RES, attno, Wp, projbias, nullptr, x, nullptr,
                    MROWS, 768, 768, 768, stream);
        // MLP
        ln_kernel<bf16_t><<<MROWS, 256, 0, stream>>>(x, ln2g, ln2b, h, 1);
        launch_gemm(EP_GELU, h, W1, fc1bias, hid, nullptr, nullptr,
                    MROWS, 3072, 768, 3072, stream);
        if (warm)
            launch_gemm(EP_RES, hid, W2, fc2bias, nullptr, x, nullptr,
                        MROWS, 768, 3072, 768, stream);
        else
            launch_gemm(EP_RESMASK, hid, W2, fc2bias, nullptr, x, maskm,
                        MROWS, 768, 3072, 768, stream);
    }

    // ---- final LN (cls rows only) + head -> fp32 d_out ----
    ln_kernel<bf16_t><<<NB, 256, 0, stream>>>(x, norm_g, norm_b, hcls, NTOK);
    launch_gemm(EP_F32, hcls, wthead, head_b, d_out, nullptr, nullptr,
                NB, 1000, 768, 1000, stream);
}

// Round 2
// 5521.186 us; speedup vs baseline: 1.2047x; 1.2047x over previous
//
#include <hip/hip_runtime.h>
#include <hip/hip_bf16.h>
#include <math.h>

// ---------------------------------------------------------------------------
// MaskedViT forward. R6: R5 (6651 us, verified) + gate path rework:
// gate_gemm_f32 (99 blocks, 4.3% occupancy, 148 us x10) + gate_dot fused into
// one kernel: 394 blocks, reg-blocked 2x4 per thread, ds_read_b128 W-tile,
// in-register gelu+dot(w2)+shfl reduce. fp32 accumulation order over k is
// identical to the verified kernel (rank safety for top-118).
// ---------------------------------------------------------------------------

typedef __bf16 bf16_t;
typedef __attribute__((ext_vector_type(8))) __bf16 bf16x8;
typedef __attribute__((ext_vector_type(4))) float f32x4;

#define DI __device__ __forceinline__

constexpr int NB     = 32;
constexpr int NTOK   = 197;
constexpr int DMODEL = 768;
constexpr int NHEAD  = 12;
constexpr int HDIM   = 64;
constexpr int HIDN   = 3072;
constexpr int GHID   = 128;
constexpr int MROWS  = NB * NTOK;   // 6304
constexpr int PROWS  = NB * 196;    // 6272
constexpr int NLAYER = 12;          // 2 warm + 10 dyn
constexpr int KTOP   = 118;
constexpr float ATT_SCALE = 0.125f;           // HD^-0.5
constexpr float LNEPS  = 1e-5f;
constexpr float LOGEPS = -13.815510558f;      // log(1e-6)

DI f32x4 mfma16(bf16x8 a, bf16x8 b, f32x4 c) {
    return __builtin_amdgcn_mfma_f32_16x16x32_bf16(a, b, c, 0, 0, 0);
}

// async global->LDS, 16B per lane. LDS dest must be wave-uniform base;
// HW writes lane's 16B at base + lane*16.
DI void gld_lds16(const void* g, void* l) {
    __builtin_amdgcn_global_load_lds(
        (__attribute__((address_space(1))) void*)(g),
        (__attribute__((address_space(3))) void*)(l), 16, 0, 0);
}

// ------------------------------- GEMM --------------------------------------
// C[M,N] = epilogue(A[M,K] @ Wt[N,K]^T + bias[N]); A,Wt bf16, acc fp32.
// 128x128 tile, BK=32, 4 waves in 2x2, each wave 64x64 (4x4 MFMA frags).
// Staging via global_load_lds width=16; OOB rows CLAMPED (valid reads,
// results discarded in epilogue).
enum { EP_BF16 = 0, EP_GELU = 1, EP_RES = 2, EP_RESMASK = 3, EP_F32 = 4 };

template<int MODE>
__global__ __launch_bounds__(256)
void gemm_bf16(const bf16_t* __restrict__ A, const bf16_t* __restrict__ Wt,
               const float* __restrict__ bias, void* __restrict__ Cout,
               float* __restrict__ resid, const float* __restrict__ rowmask,
               int M, int N, int K, int ldc)
{
    __shared__ __align__(16) bf16_t As[128 * 32];
    __shared__ __align__(16) bf16_t Bs[128 * 32];
    const int tid  = threadIdx.x;
    const int lane = tid & 63;
    const int wave = tid >> 6;
    const int wm = wave >> 1, wn = wave & 1;
    const int quad = lane >> 4, l16 = lane & 15;
    const int m0 = blockIdx.y * 128;
    const int n0 = blockIdx.x * 128;

    f32x4 zero4 = {0.f, 0.f, 0.f, 0.f};
    f32x4 acc[4][4];
#pragma unroll
    for (int i = 0; i < 4; ++i)
#pragma unroll
        for (int j = 0; j < 4; ++j) acc[i][j] = zero4;

    // per-lane global source rows (clamped) and wave-uniform LDS dests.
    const int rh  = tid >> 2;              // 0..63
    const int seg = tid & 3;               // 0..3 (8 bf16 each)
    const int rA0 = min(m0 + rh,      M - 1);
    const int rA1 = min(m0 + 64 + rh, M - 1);
    const int rB0 = min(n0 + rh,      N - 1);
    const int rB1 = min(n0 + 64 + rh, N - 1);
    const bf16_t* pA0 = A  + (size_t)rA0 * K + seg * 8;
    const bf16_t* pA1 = A  + (size_t)rA1 * K + seg * 8;
    const bf16_t* pB0 = Wt + (size_t)rB0 * K + seg * 8;
    const bf16_t* pB1 = Wt + (size_t)rB1 * K + seg * 8;
    bf16_t* lA0 = As + wave * 512;
    bf16_t* lA1 = As + 2048 + wave * 512;
    bf16_t* lB0 = Bs + wave * 512;
    bf16_t* lB1 = Bs + 2048 + wave * 512;

    const int nkt = K >> 5;
    for (int kt = 0; kt < nkt; ++kt) {
        const int kb = kt << 5;
        __syncthreads();   // previous iter's ds_reads done before overwrite
        gld_lds16(pA0 + kb, lA0);
        gld_lds16(pA1 + kb, lA1);
        gld_lds16(pB0 + kb, lB0);
        gld_lds16(pB1 + kb, lB1);
        __syncthreads();   // barrier drains vmcnt -> tile visible

        bf16x8 af[4], bfr[4];
#pragma unroll
        for (int i = 0; i < 4; ++i)
            af[i] = *reinterpret_cast<const bf16x8*>(As + (wm * 64 + i * 16 + l16) * 32 + quad * 8);
#pragma unroll
        for (int j = 0; j < 4; ++j)
            bfr[j] = *reinterpret_cast<const bf16x8*>(Bs + (wn * 64 + j * 16 + l16) * 32 + quad * 8);
#pragma unroll
        for (int i = 0; i < 4; ++i)
#pragma unroll
            for (int j = 0; j < 4; ++j)
                acc[i][j] = mfma16(af[i], bfr[j], acc[i][j]);
    }

    // epilogue: C/D layout col=lane&15, row=quad*4+reg
#pragma unroll
    for (int j = 0; j < 4; ++j) {
        int c = n0 + wn * 64 + j * 16 + l16;
        if (c >= N) continue;
        float bj = bias ? bias[c] : 0.f;
#pragma unroll
        for (int i = 0; i < 4; ++i) {
#pragma unroll
            for (int r = 0; r < 4; ++r) {
                int mr = m0 + wm * 64 + i * 16 + quad * 4 + r;
                if (mr >= M) continue;
                float v = acc[i][j][r] + bj;
                size_t off = (size_t)mr * ldc + c;
                if (MODE == EP_BF16) {
                    ((bf16_t*)Cout)[off] = (bf16_t)v;
                } else if (MODE == EP_GELU) {
                    float g = 0.5f * v * (1.f + erff(v * 0.70710678118f));
                    ((bf16_t*)Cout)[off] = (bf16_t)g;
                } else if (MODE == EP_F32) {
                    ((float*)Cout)[off] = v;
                } else if (MODE == EP_RES) {
                    resid[off] += v;
                } else { // EP_RESMASK
                    resid[off] += v * rowmask[mr];
                }
            }
        }
    }
}

// ------------------------------ LayerNorm ----------------------------------
DI float block_reduce_sum(float val, float* sh) {
#pragma unroll
    for (int off = 32; off; off >>= 1) val += __shfl_down(val, off, 64);
    __syncthreads();
    if ((threadIdx.x & 63) == 0) sh[threadIdx.x >> 6] = val;
    __syncthreads();
    return sh[0] + sh[1] + sh[2] + sh[3];
}

// in row = blockIdx.x * row_mul (fp32); OUT = bf16 or fp32
template<typename OUT>
__global__ __launch_bounds__(256)
void ln_kernel(const float* __restrict__ X, const float* __restrict__ g,
               const float* __restrict__ bta, OUT* __restrict__ H, int row_mul)
{
    __shared__ float sh[4];
    const int t = threadIdx.x;
    const float* xr = X + (size_t)blockIdx.x * row_mul * DMODEL;
    float v[3];
#pragma unroll
    for (int i = 0; i < 3; ++i) v[i] = xr[t + i * 256];
    float s = v[0] + v[1] + v[2];
    s = block_reduce_sum(s, sh);
    float mu = s * (1.f / DMODEL);
    float q = 0.f;
#pragma unroll
    for (int i = 0; i < 3; ++i) { float d = v[i] - mu; q += d * d; }
    q = block_reduce_sum(q, sh);
    float rstd = rsqrtf(q * (1.f / DMODEL) + LNEPS);
    OUT* hr = H + (size_t)blockIdx.x * DMODEL;
#pragma unroll
    for (int i = 0; i < 3; ++i) {
        int c = t + i * 256;
        hr[c] = (OUT)((v[i] - mu) * rstd * g[c] + bta[c]);
    }
}

// ------------------------------ Attention ----------------------------------
__global__ __launch_bounds__(256)
void attn_kernel(const bf16_t* __restrict__ qkv,   // [B][197][3][768]
                 const float* __restrict__ addmask, // [B][197] or null
                 bf16_t* __restrict__ outp)          // [B][197][768]
{
    constexpr int KP = 232;  // padded key stride (>=224, 16B-multiple rows)
    __shared__ __align__(16) bf16_t Vt[64 * KP];       // Vt[hd][key]
    __shared__ __align__(16) bf16_t Ps[4][16 * KP];    // per-wave P[q][key]
    const int b = blockIdx.z, h = blockIdx.y, qt = blockIdx.x;
    const int tid = threadIdx.x, wave = tid >> 6, lane = tid & 63;
    const int quad = lane >> 4, l16 = lane & 15;

    // stage V^T (zero-padded keys 197..223)
    {
        int d = tid & 63, ng = tid >> 6;
        for (int n = ng; n < 224; n += 4) {
            bf16_t v = (bf16_t)0.f;
            if (n < 197)
                v = qkv[(((size_t)b * NTOK + n) * 3 + 2) * DMODEL + h * HDIM + d];
            Vt[d * KP + n] = v;
        }
    }
    __syncthreads();

    // Q fragments straight from global (A-op: m=lane&15, k=quad*8+j)
    const int qbase = qt * 64 + wave * 16;
    const int qrow = qbase + l16;
    const int qc = qrow < 196 ? qrow : 196;
    bf16x8 aq[2];
#pragma unroll
    for (int t = 0; t < 2; ++t)
        aq[t] = *reinterpret_cast<const bf16x8*>(
            qkv + (((size_t)b * NTOK + qc) * 3 + 0) * DMODEL + h * HDIM + t * 32 + quad * 8);

    // scores: 13 key-tiles of 16
    float sreg[13][4];
#pragma unroll
    for (int kt = 0; kt < 13; ++kt) {
        int key = kt * 16 + l16;
        int kc = key < 196 ? key : 196;
        const bf16_t* kb = qkv + (((size_t)b * NTOK + kc) * 3 + 1) * DMODEL + h * HDIM;
        bf16x8 kf0 = *reinterpret_cast<const bf16x8*>(kb + quad * 8);
        bf16x8 kf1 = *reinterpret_cast<const bf16x8*>(kb + 32 + quad * 8);
        f32x4 s = {0.f, 0.f, 0.f, 0.f};
        s = mfma16(aq[0], kf0, s);
        s = mfma16(aq[1], kf1, s);
        float am = addmask ? addmask[b * NTOK + kc] : 0.f;
        bool kvalid = key < 197;
#pragma unroll
        for (int r = 0; r < 4; ++r)
            sreg[kt][r] = kvalid ? (s[r] * ATT_SCALE + am) : -1e30f;
    }

    // softmax rows (row = quad*4+r, spread over the 16 lanes of the quad)
    float psum[4];
#pragma unroll
    for (int r = 0; r < 4; ++r) {
        float mx = -1e30f;
#pragma unroll
        for (int kt = 0; kt < 13; ++kt) mx = fmaxf(mx, sreg[kt][r]);
#pragma unroll
        for (int d = 1; d < 16; d <<= 1) mx = fmaxf(mx, __shfl_xor(mx, d, 64));
        float sum = 0.f;
#pragma unroll
        for (int kt = 0; kt < 13; ++kt) {
            float p = expf(sreg[kt][r] - mx);
            sreg[kt][r] = p;
            sum += p;
        }
#pragma unroll
        for (int d = 1; d < 16; d <<= 1) sum += __shfl_xor(sum, d, 64);
        psum[r] = sum;
    }

    // write P to LDS (C-layout -> A-layout transform), zero-pad cols 208..223
#pragma unroll
    for (int kt = 0; kt < 13; ++kt)
#pragma unroll
        for (int r = 0; r < 4; ++r)
            Ps[wave][(quad * 4 + r) * KP + kt * 16 + l16] = (bf16_t)sreg[kt][r];
    {
        int rr = lane & 15, c0 = 208 + (lane >> 4) * 4;
#pragma unroll
        for (int i = 0; i < 4; ++i) Ps[wave][rr * KP + c0 + i] = (bf16_t)0.f;
    }
    __syncthreads();   // P-write -> PV-read ordering

    // O = P @ V  (7 K-steps of 32 keys)
    f32x4 o[4];
#pragma unroll
    for (int j = 0; j < 4; ++j) o[j] = (f32x4){0.f, 0.f, 0.f, 0.f};
#pragma unroll
    for (int ks = 0; ks < 7; ++ks) {
        bf16x8 ap = *reinterpret_cast<const bf16x8*>(&Ps[wave][l16 * KP + ks * 32 + quad * 8]);
#pragma unroll
        for (int j = 0; j < 4; ++j) {
            bf16x8 vf = *reinterpret_cast<const bf16x8*>(&Vt[(j * 16 + l16) * KP + ks * 32 + quad * 8]);
            o[j] = mfma16(ap, vf, o[j]);
        }
    }

    // normalize + store
#pragma unroll
    for (int r = 0; r < 4; ++r) {
        int q = qbase + quad * 4 + r;
        if (q < 197) {
            float rs = 1.f / fmaxf(psum[r], 1e-20f);
#pragma unroll
            for (int j = 0; j < 4; ++j)
                outp[((size_t)b * NTOK + q) * DMODEL + h * HDIM + j * 16 + l16] =
                    (bf16_t)(o[j][r] * rs);
        }
    }
}

// --------------------------- small kernels ---------------------------------
__global__ __launch_bounds__(256)
void transpose_f32(const float* __restrict__ src, bf16_t* __restrict__ dst, int K, int N)
{
    __shared__ bf16_t tile[64][65];
    const size_t ls = (size_t)K * N * blockIdx.z;
    int k0 = blockIdx.y * 64, n0 = blockIdx.x * 64;
    int c = threadIdx.x & 63, r0 = threadIdx.x >> 6;
#pragma unroll
    for (int i = 0; i < 16; ++i) {
        int r = r0 + i * 4;
        tile[r][c] = (k0 + r < K && n0 + c < N)
                   ? (bf16_t)src[ls + (size_t)(k0 + r) * N + n0 + c] : (bf16_t)0.f;
    }
    __syncthreads();
#pragma unroll
    for (int i = 0; i < 16; ++i) {
        int r = r0 + i * 4;  // n-dim
        if (n0 + r < N && k0 + c < K) dst[ls + (size_t)(n0 + r) * K + k0 + c] = tile[c][r];
    }
}

__global__ void cvt_f32_bf16(const float* __restrict__ src, bf16_t* __restrict__ dst, int n)
{
    int i = blockIdx.x * 256 + threadIdx.x;
    if (i < n) dst[i] = (bf16_t)src[i];
}

__global__ void im2col_kernel(const float* __restrict__ img, bf16_t* __restrict__ Ap)
{
    int idx = blockIdx.x * 256 + threadIdx.x;
    if (idx >= PROWS * 768) return;
    int col = idx % 768, row = idx / 768;
    int b = row / 196, t = row % 196;
    int gi = t / 14, gj = t % 14;
    int c = col >> 8, rr = col & 255, p = rr >> 4, q = rr & 15;
    Ap[idx] = (bf16_t)img[(((size_t)b * 3 + c) * 224 + gi * 16 + p) * 224 + gj * 16 + q];
}

__global__ void assemble_x(const float* __restrict__ patch, const float* __restrict__ cls,
                           const float* __restrict__ pos, float* __restrict__ X)
{
    int idx = blockIdx.x * 256 + threadIdx.x;
    if (idx >= MROWS * DMODEL) return;
    int d = idx % DMODEL, rest = idx / DMODEL;
    int n = rest % NTOK, b = rest / NTOK;
    float v;
    if (n == 0) v = cls[d] + pos[d];
    else        v = patch[((size_t)b * 196 + (n - 1)) * DMODEL + d] + pos[(size_t)n * DMODEL + d];
    X[idx] = v;
}

// ---- gate path (fp32 end-to-end; top-k ranks must match np exactly) -------
// Fused: logits[m] = dot(gelu(A[m]@W1 + b1), w2) + b2, all fp32.
// 16 rows/block (M=6304=394*16, no guards), 256 threads.
// Thread (rg=tid>>5, tx=tid&31): rows rg*2, rg*2+1; cols tx*4..tx*4+3.
// fp32 accumulation over k is strictly ascending (matches verified kernel).
__global__ __launch_bounds__(256)
void gate_fused_f32(const float* __restrict__ A, const float* __restrict__ W1,
                    const float* __restrict__ b1, const float* __restrict__ w2,
                    const float* __restrict__ b2, float* __restrict__ logits)
{
    __shared__ __align__(16) float As[16][64];
    __shared__ __align__(16) float Ws[64][128];
    const int tid = threadIdx.x;
    const int m0 = blockIdx.x * 16;
    const int tx = tid & 31;       // col group: cols tx*4..tx*4+3
    const int rg = tid >> 5;       // 0..7 -> rows rg*2, rg*2+1
    f32x4 acc0 = {0.f, 0.f, 0.f, 0.f};
    f32x4 acc1 = {0.f, 0.f, 0.f, 0.f};
    for (int k0 = 0; k0 < 768; k0 += 64) {
        __syncthreads();
        {   // stage A-tile: 1024 floats = 256 float4 (1/thread)
            int idx = tid * 4;
            int r = idx >> 6, c = idx & 63;
            *reinterpret_cast<f32x4*>(&As[r][c]) =
                *reinterpret_cast<const f32x4*>(&A[(size_t)(m0 + r) * 768 + k0 + c]);
        }
#pragma unroll
        for (int i = 0; i < 8; ++i) {  // stage W-tile: 8192 floats = 8 float4/thread
            int idx = (tid + i * 256) * 4;
            int r = idx >> 7, c = idx & 127;
            *reinterpret_cast<f32x4*>(&Ws[r][c]) =
                *reinterpret_cast<const f32x4*>(&W1[(size_t)(k0 + r) * 128 + c]);
        }
        __syncthreads();
#pragma unroll
        for (int kk = 0; kk < 64; ++kk) {
            float a0 = As[rg * 2 + 0][kk];   // broadcast (2 addrs/wave: free)
            float a1 = As[rg * 2 + 1][kk];
            f32x4 w = *reinterpret_cast<const f32x4*>(&Ws[kk][tx * 4]);  // b128, conflict-free
#pragma unroll
            for (int j = 0; j < 4; ++j) {
                acc0[j] += a0 * w[j];
                acc1[j] += a1 * w[j];
            }
        }
    }
    // epilogue: bias + gelu + dot(w2), reduce across the 32 tx lanes
    float s0 = 0.f, s1 = 0.f;
#pragma unroll
    for (int j = 0; j < 4; ++j) {
        int c = tx * 4 + j;
        float bj = b1[c], wj = w2[c];
        float v0 = acc0[j] + bj;
        float v1 = acc1[j] + bj;
        s0 += 0.5f * v0 * (1.f + erff(v0 * 0.70710678118f)) * wj;
        s1 += 0.5f * v1 * (1.f + erff(v1 * 0.70710678118f)) * wj;
    }
#pragma unroll
    for (int d = 1; d < 32; d <<= 1) {
        s0 += __shfl_xor(s0, d, 64);
        s1 += __shfl_xor(s1, d, 64);
    }
    if (tx == 0) {
        logits[m0 + rg * 2 + 0] = s0 + b2[0];
        logits[m0 + rg * 2 + 1] = s1 + b2[0];
    }
}

// exact top-118 of logits[b,1:197] by rank counting (lax.top_k tie-break: lower index)
__global__ __launch_bounds__(256)
void topk_kernel(const float* __restrict__ logits, float* __restrict__ maskm,
                 float* __restrict__ addm)
{
    __shared__ float ls[196];
    int b = blockIdx.x, t = threadIdx.x;
    if (t < 196) ls[t] = logits[b * NTOK + 1 + t];
    __syncthreads();
    if (t < 196) {
        float li = ls[t];
        int cnt = 0;
        for (int j = 0; j < 196; ++j) {
            float lj = ls[j];
            cnt += (lj > li) || (lj == li && j < t);
        }
        bool sel = cnt < KTOP;
        maskm[b * NTOK + 1 + t] = sel ? 1.f : 0.f;
        addm[b * NTOK + 1 + t]  = sel ? 0.f : LOGEPS;
    }
    if (t == 0) { maskm[b * NTOK] = 1.f; addm[b * NTOK] = 0.f; }
}

__global__ void fill_sentinel(float* out, int n)
{
    int i = blockIdx.x * 256 + threadIdx.x;
    if (i < n) out[i] = 12345.0f;
}

// ------------------------------- host --------------------------------------
static void launch_gemm(int mode, const bf16_t* A, const bf16_t* Wt, const float* bias,
                        void* C, float* resid, const float* rowmask,
                        int M, int N, int K, int ldc, hipStream_t s)
{
    dim3 grid((N + 127) / 128, (M + 127) / 128);
    dim3 blk(256);
    switch (mode) {
    case EP_BF16:    gemm_bf16<EP_BF16><<<grid, blk, 0, s>>>(A, Wt, bias, C, resid, rowmask, M, N, K, ldc); break;
    case EP_GELU:    gemm_bf16<EP_GELU><<<grid, blk, 0, s>>>(A, Wt, bias, C, resid, rowmask, M, N, K, ldc); break;
    case EP_RES:     gemm_bf16<EP_RES><<<grid, blk, 0, s>>>(A, Wt, bias, C, resid, rowmask, M, N, K, ldc); break;
    case EP_RESMASK: gemm_bf16<EP_RESMASK><<<grid, blk, 0, s>>>(A, Wt, bias, C, resid, rowmask, M, N, K, ldc); break;
    case EP_F32:     gemm_bf16<EP_F32><<<grid, blk, 0, s>>>(A, Wt, bias, C, resid, rowmask, M, N, K, ldc); break;
    }
}

extern "C" void kernel_launch(void* const* d_in, const int* in_sizes, int n_in,
                              void* d_out, int out_size, void* d_ws, size_t ws_size,
                              hipStream_t stream)
{
    (void)in_sizes; (void)n_in;
    const float* images   = (const float*)d_in[0];
    const float* patch_w  = (const float*)d_in[1];
    const float* patch_b  = (const float*)d_in[2];
    const float* cls_tok  = (const float*)d_in[3];
    const float* pos_emb  = (const float*)d_in[4];
    const float* w_ln1_g  = (const float*)d_in[5];
    const float* w_ln1_b  = (const float*)d_in[6];
    const float* w_qkv_w  = (const float*)d_in[7];
    const float* w_qkv_b  = (const float*)d_in[8];
    const float* w_proj_w = (const float*)d_in[9];
    const float* w_proj_b = (const float*)d_in[10];
    const float* w_ln2_g  = (const float*)d_in[11];
    const float* w_ln2_b  = (const float*)d_in[12];
    const float* w_fc1_w  = (const float*)d_in[13];
    const float* w_fc1_b  = (const float*)d_in[14];
    const float* w_fc2_w  = (const float*)d_in[15];
    const float* w_fc2_b  = (const float*)d_in[16];
    const float* d_ln1_g  = (const float*)d_in[17];
    const float* d_ln1_b  = (const float*)d_in[18];
    const float* d_qkv_w  = (const float*)d_in[19];
    const float* d_qkv_b  = (const float*)d_in[20];
    const float* d_proj_w = (const float*)d_in[21];
    const float* d_proj_b = (const float*)d_in[22];
    const float* d_ln2_g  = (const float*)d_in[23];
    const float* d_ln2_b  = (const float*)d_in[24];
    const float* d_fc1_w  = (const float*)d_in[25];
    const float* d_fc1_b  = (const float*)d_in[26];
    const float* d_fc2_w  = (const float*)d_in[27];
    const float* d_fc2_b  = (const float*)d_in[28];
    const float* d_gln_g  = (const float*)d_in[29];
    const float* d_gln_b  = (const float*)d_in[30];
    const float* d_gw1    = (const float*)d_in[31];
    const float* d_gb1    = (const float*)d_in[32];
    const float* d_gw2    = (const float*)d_in[33];
    const float* d_gb2    = (const float*)d_in[34];
    const float* norm_g   = (const float*)d_in[35];
    const float* norm_b   = (const float*)d_in[36];
    const float* head_w   = (const float*)d_in[37];
    const float* head_b   = (const float*)d_in[38];

    // workspace layout
    char* wp = (char*)d_ws;
    auto alloc = [&](size_t bytes) -> char* {
        char* p = wp; wp += (bytes + 255) & ~(size_t)255; return p;
    };
    bf16_t* wtqkv  = (bf16_t*)alloc((size_t)NLAYER * 2304 * 768 * 2);
    bf16_t* wtproj = (bf16_t*)alloc((size_t)NLAYER * 768 * 768 * 2);
    bf16_t* wtfc1  = (bf16_t*)alloc((size_t)NLAYER * 3072 * 768 * 2);
    bf16_t* wtfc2  = (bf16_t*)alloc((size_t)NLAYER * 768 * 3072 * 2);
    bf16_t* wthead = (bf16_t*)alloc((size_t)1024 * 768 * 2);
    bf16_t* pwbf   = (bf16_t*)alloc((size_t)768 * 768 * 2);
    float*  x      = (float*)alloc((size_t)MROWS * DMODEL * 4);
    bf16_t* h      = (bf16_t*)alloc((size_t)MROWS * DMODEL * 2);
    float*  hgate  = (float*)alloc((size_t)MROWS * DMODEL * 4);
    bf16_t* hcls   = (bf16_t*)alloc((size_t)NB * DMODEL * 2);
    bf16_t* qkvb   = (bf16_t*)alloc((size_t)MROWS * 2304 * 2);
    bf16_t* attno  = (bf16_t*)alloc((size_t)MROWS * DMODEL * 2);
    bf16_t* hid    = (bf16_t*)alloc((size_t)MROWS * HIDN * 2);
    float*  logits = (float*)alloc((size_t)MROWS * 4);
    float*  maskm  = (float*)alloc((size_t)MROWS * 4);
    float*  addm   = (float*)alloc((size_t)MROWS * 4);
    size_t used = (size_t)(wp - (char*)d_ws);
    if (used > ws_size) {  // diagnostic: distinctive absmax if ws is too small
        fill_sentinel<<<(out_size + 255) / 256, 256, 0, stream>>>((float*)d_out, out_size);
        return;
    }
    // patch scratch aliases hid (patch phase precedes any MLP use)
    bf16_t* Ap = hid;                                    // [6272][768] bf16
    float* patchout = (float*)((char*)hid + (size_t)PROWS * 768 * 2); // [6272][768] f32

    // ---- weight pre-transpose ([K][N] -> [N][K] bf16) ----
    transpose_f32<<<dim3(36, 12, 2),  256, 0, stream>>>(w_qkv_w,  wtqkv,                      768, 2304);
    transpose_f32<<<dim3(36, 12, 10), 256, 0, stream>>>(d_qkv_w,  wtqkv + (size_t)2*2304*768, 768, 2304);
    transpose_f32<<<dim3(12, 12, 2),  256, 0, stream>>>(w_proj_w, wtproj,                     768, 768);
    transpose_f32<<<dim3(12, 12, 10), 256, 0, stream>>>(d_proj_w, wtproj + (size_t)2*768*768, 768, 768);
    transpose_f32<<<dim3(48, 12, 2),  256, 0, stream>>>(w_fc1_w,  wtfc1,                      768, 3072);
    transpose_f32<<<dim3(48, 12, 10), 256, 0, stream>>>(d_fc1_w,  wtfc1 + (size_t)2*3072*768, 768, 3072);
    transpose_f32<<<dim3(12, 48, 2),  256, 0, stream>>>(w_fc2_w,  wtfc2,                      3072, 768);
    transpose_f32<<<dim3(12, 48, 10), 256, 0, stream>>>(d_fc2_w,  wtfc2 + (size_t)2*768*3072, 3072, 768);
    transpose_f32<<<dim3(16, 12, 1),  256, 0, stream>>>(head_w,   wthead,                     768, 1000);
    cvt_f32_bf16<<<(768 * 768 + 255) / 256, 256, 0, stream>>>(patch_w, pwbf, 768 * 768);

    // ---- patch embed + assemble ----
    im2col_kernel<<<(PROWS * 768 + 255) / 256, 256, 0, stream>>>(images, Ap);
    launch_gemm(EP_F32, Ap, pwbf, patch_b, patchout, nullptr, nullptr,
                PROWS, 768, 768, 768, stream);
    assemble_x<<<(MROWS * DMODEL + 255) / 256, 256, 0, stream>>>(patchout, cls_tok, pos_emb, x);

    // ---- transformer layers ----
    for (int L = 0; L < NLAYER; ++L) {
        bool warm = (L < 2);
        int li = warm ? L : (L - 2);
        const float* ln1g = warm ? w_ln1_g + li*768 : d_ln1_g + li*768;
        const float* ln1b = warm ? w_ln1_b + li*768 : d_ln1_b + li*768;
        const float* ln2g = warm ? w_ln2_g + li*768 : d_ln2_g + li*768;
        const float* ln2b = warm ? w_ln2_b + li*768 : d_ln2_b + li*768;
        const float* qkvbias  = warm ? w_qkv_b + li*2304 : d_qkv_b + li*2304;
        const float* projbias = warm ? w_proj_b + li*768 : d_proj_b + li*768;
        const float* fc1bias  = warm ? w_fc1_b + (size_t)li*3072 : d_fc1_b + (size_t)li*3072;
        const float* fc2bias  = warm ? w_fc2_b + li*768 : d_fc2_b + li*768;
        const bf16_t* Wq = wtqkv + (size_t)L * 2304 * 768;
        const bf16_t* Wp = wtproj + (size_t)L * 768 * 768;
        const bf16_t* W1 = wtfc1 + (size_t)L * 3072 * 768;
        const bf16_t* W2 = wtfc2 + (size_t)L * 768 * 3072;

        if (!warm) {
            // gate: LN -> fused fc1+gelu+dot -> top-118 mask   (all fp32)
            ln_kernel<float><<<MROWS, 256, 0, stream>>>(x, d_gln_g + li*768, d_gln_b + li*768, hgate, 1);
            gate_fused_f32<<<MROWS / 16, 256, 0, stream>>>(
                hgate, d_gw1 + (size_t)li*768*128, d_gb1 + li*128,
                d_gw2 + (size_t)li*128, d_gb2 + li, logits);
            topk_kernel<<<NB, 256, 0, stream>>>(logits, maskm, addm);
        }
        // attention
        ln_kernel<bf16_t><<<MROWS, 256, 0, stream>>>(x, ln1g, ln1b, h, 1);
        launch_gemm(EP_BF16, h, Wq, qkvbias, qkvb, nullptr, nullptr,
                    MROWS, 2304, 768, 2304, stream);
        attn_kernel<<<dim3(4, NHEAD, NB), 256, 0, stream>>>(qkvb, warm ? nullptr : addm, attno);
        launch_gemm(EP_RES, attno, Wp, projbias, nullptr, x, nullptr,
                    MROWS, 768, 768, 768, stream);
        // MLP
        ln_kernel<bf16_t><<<MROWS, 256, 0, stream>>>(x, ln2g, ln2b, h, 1);
        launch_gemm(EP_GELU, h, W1, fc1bias, hid, nullptr, nullptr,
                    MROWS, 3072, 768, 3072, stream);
        if (warm)
            launch_gemm(EP_RES, hid, W2, fc2bias, nullptr, x, nullptr,
                        MROWS, 768, 3072, 768, stream);
        else
            launch_gemm(EP_RESMASK, hid, W2, fc2bias, nullptr, x, maskm,
                        MROWS, 768, 3072, 768, stream);
    }

    // ---- final LN (cls rows only) + head -> fp32 d_out ----
    ln_kernel<bf16_t><<<NB, 256, 0, stream>>>(x, norm_g, norm_b, hcls, NTOK);
    launch_gemm(EP_F32, hcls, wthead, head_b, d_out, nullptr, nullptr,
                NB, 1000, 768, 1000, stream);
}

// Round 3
// 5384.414 us; speedup vs baseline: 1.2353x; 1.0254x over previous
//
#include <hip/hip_runtime.h>
#include <hip/hip_bf16.h>
#include <math.h>

// ---------------------------------------------------------------------------
// MaskedViT forward. R7: R6 (5521 us, verified) + gemm_bf16 double-buffered
// LDS prefetch (stage tile k+1 while computing tile k; one barrier per K-step
// instead of two). Rationale: fc2/proj grids are ~300 blocks on 256 CUs ->
// 1 block/CU, no inter-block latency hiding; counters showed MfmaUtil 10.7%,
// VALUBusy 16.5%, HBM 18.5% (all low = latency-bound on the staging drain).
// ---------------------------------------------------------------------------

typedef __bf16 bf16_t;
typedef __attribute__((ext_vector_type(8))) __bf16 bf16x8;
typedef __attribute__((ext_vector_type(4))) float f32x4;

#define DI __device__ __forceinline__

constexpr int NB     = 32;
constexpr int NTOK   = 197;
constexpr int DMODEL = 768;
constexpr int NHEAD  = 12;
constexpr int HDIM   = 64;
constexpr int HIDN   = 3072;
constexpr int GHID   = 128;
constexpr int MROWS  = NB * NTOK;   // 6304
constexpr int PROWS  = NB * 196;    // 6272
constexpr int NLAYER = 12;          // 2 warm + 10 dyn
constexpr int KTOP   = 118;
constexpr float ATT_SCALE = 0.125f;           // HD^-0.5
constexpr float LNEPS  = 1e-5f;
constexpr float LOGEPS = -13.815510558f;      // log(1e-6)

DI f32x4 mfma16(bf16x8 a, bf16x8 b, f32x4 c) {
    return __builtin_amdgcn_mfma_f32_16x16x32_bf16(a, b, c, 0, 0, 0);
}

// async global->LDS, 16B per lane. LDS dest must be wave-uniform base;
// HW writes lane's 16B at base + lane*16.
DI void gld_lds16(const void* g, void* l) {
    __builtin_amdgcn_global_load_lds(
        (__attribute__((address_space(1))) void*)(g),
        (__attribute__((address_space(3))) void*)(l), 16, 0, 0);
}

// ------------------------------- GEMM --------------------------------------
// C[M,N] = epilogue(A[M,K] @ Wt[N,K]^T + bias[N]); A,Wt bf16, acc fp32.
// 128x128 tile, BK=32, 4 waves in 2x2, each wave 64x64 (4x4 MFMA frags).
// Double-buffered global_load_lds staging (prefetch 1 K-tile ahead); one
// __syncthreads per K-step (drains vmcnt -> publishes prefetch AND protects
// buffer reuse). OOB rows CLAMPED (valid reads, results discarded).
enum { EP_BF16 = 0, EP_GELU = 1, EP_RES = 2, EP_RESMASK = 3, EP_F32 = 4 };

template<int MODE>
__global__ __launch_bounds__(256)
void gemm_bf16(const bf16_t* __restrict__ A, const bf16_t* __restrict__ Wt,
               const float* __restrict__ bias, void* __restrict__ Cout,
               float* __restrict__ resid, const float* __restrict__ rowmask,
               int M, int N, int K, int ldc)
{
    __shared__ __align__(16) bf16_t As[2][128 * 32];
    __shared__ __align__(16) bf16_t Bs[2][128 * 32];
    const int tid  = threadIdx.x;
    const int lane = tid & 63;
    const int wave = tid >> 6;
    const int wm = wave >> 1, wn = wave & 1;
    const int quad = lane >> 4, l16 = lane & 15;
    const int m0 = blockIdx.y * 128;
    const int n0 = blockIdx.x * 128;

    f32x4 zero4 = {0.f, 0.f, 0.f, 0.f};
    f32x4 acc[4][4];
#pragma unroll
    for (int i = 0; i < 4; ++i)
#pragma unroll
        for (int j = 0; j < 4; ++j) acc[i][j] = zero4;

    // per-lane global source rows (clamped) and wave-uniform LDS offsets.
    const int rh  = tid >> 2;              // 0..63
    const int seg = tid & 3;               // 0..3 (8 bf16 each)
    const int rA0 = min(m0 + rh,      M - 1);
    const int rA1 = min(m0 + 64 + rh, M - 1);
    const int rB0 = min(n0 + rh,      N - 1);
    const int rB1 = min(n0 + 64 + rh, N - 1);
    const bf16_t* pA0 = A  + (size_t)rA0 * K + seg * 8;
    const bf16_t* pA1 = A  + (size_t)rA1 * K + seg * 8;
    const bf16_t* pB0 = Wt + (size_t)rB0 * K + seg * 8;
    const bf16_t* pB1 = Wt + (size_t)rB1 * K + seg * 8;
    const int lofs0 = wave * 512;          // within a buffer
    const int lofs1 = 2048 + wave * 512;

    const int nkt = K >> 5;
    // prologue: stage K-tile 0 into buffer 0
    gld_lds16(pA0, As[0] + lofs0);
    gld_lds16(pA1, As[0] + lofs1);
    gld_lds16(pB0, Bs[0] + lofs0);
    gld_lds16(pB1, Bs[0] + lofs1);
    __syncthreads();   // vmcnt(0) drain -> tile 0 visible

    for (int kt = 0; kt < nkt; ++kt) {
        const int cur = kt & 1;
        if (kt + 1 < nkt) {            // prefetch next tile into other buffer
            const int kb = (kt + 1) << 5;
            gld_lds16(pA0 + kb, As[cur ^ 1] + lofs0);
            gld_lds16(pA1 + kb, As[cur ^ 1] + lofs1);
            gld_lds16(pB0 + kb, Bs[cur ^ 1] + lofs0);
            gld_lds16(pB1 + kb, Bs[cur ^ 1] + lofs1);
        }
        bf16x8 af[4], bfr[4];
#pragma unroll
        for (int i = 0; i < 4; ++i)
            af[i] = *reinterpret_cast<const bf16x8*>(As[cur] + (wm * 64 + i * 16 + l16) * 32 + quad * 8);
#pragma unroll
        for (int j = 0; j < 4; ++j)
            bfr[j] = *reinterpret_cast<const bf16x8*>(Bs[cur] + (wn * 64 + j * 16 + l16) * 32 + quad * 8);
#pragma unroll
        for (int i = 0; i < 4; ++i)
#pragma unroll
            for (int j = 0; j < 4; ++j)
                acc[i][j] = mfma16(af[i], bfr[j], acc[i][j]);
        __syncthreads();   // publishes prefetch; protects buffer for next stage
    }

    // epilogue: C/D layout col=lane&15, row=quad*4+reg
#pragma unroll
    for (int j = 0; j < 4; ++j) {
        int c = n0 + wn * 64 + j * 16 + l16;
        if (c >= N) continue;
        float bj = bias ? bias[c] : 0.f;
#pragma unroll
        for (int i = 0; i < 4; ++i) {
#pragma unroll
            for (int r = 0; r < 4; ++r) {
                int mr = m0 + wm * 64 + i * 16 + quad * 4 + r;
                if (mr >= M) continue;
                float v = acc[i][j][r] + bj;
                size_t off = (size_t)mr * ldc + c;
                if (MODE == EP_BF16) {
                    ((bf16_t*)Cout)[off] = (bf16_t)v;
                } else if (MODE == EP_GELU) {
                    float g = 0.5f * v * (1.f + erff(v * 0.70710678118f));
                    ((bf16_t*)Cout)[off] = (bf16_t)g;
                } else if (MODE == EP_F32) {
                    ((float*)Cout)[off] = v;
                } else if (MODE == EP_RES) {
                    resid[off] += v;
                } else { // EP_RESMASK
                    resid[off] += v * rowmask[mr];
                }
            }
        }
    }
}

// ------------------------------ LayerNorm ----------------------------------
DI float block_reduce_sum(float val, float* sh) {
#pragma unroll
    for (int off = 32; off; off >>= 1) val += __shfl_down(val, off, 64);
    __syncthreads();
    if ((threadIdx.x & 63) == 0) sh[threadIdx.x >> 6] = val;
    __syncthreads();
    return sh[0] + sh[1] + sh[2] + sh[3];
}

// in row = blockIdx.x * row_mul (fp32); OUT = bf16 or fp32
template<typename OUT>
__global__ __launch_bounds__(256)
void ln_kernel(const float* __restrict__ X, const float* __restrict__ g,
               const float* __restrict__ bta, OUT* __restrict__ H, int row_mul)
{
    __shared__ float sh[4];
    const int t = threadIdx.x;
    const float* xr = X + (size_t)blockIdx.x * row_mul * DMODEL;
    float v[3];
#pragma unroll
    for (int i = 0; i < 3; ++i) v[i] = xr[t + i * 256];
    float s = v[0] + v[1] + v[2];
    s = block_reduce_sum(s, sh);
    float mu = s * (1.f / DMODEL);
    float q = 0.f;
#pragma unroll
    for (int i = 0; i < 3; ++i) { float d = v[i] - mu; q += d * d; }
    q = block_reduce_sum(q, sh);
    float rstd = rsqrtf(q * (1.f / DMODEL) + LNEPS);
    OUT* hr = H + (size_t)blockIdx.x * DMODEL;
#pragma unroll
    for (int i = 0; i < 3; ++i) {
        int c = t + i * 256;
        hr[c] = (OUT)((v[i] - mu) * rstd * g[c] + bta[c]);
    }
}

// ------------------------------ Attention ----------------------------------
__global__ __launch_bounds__(256)
void attn_kernel(const bf16_t* __restrict__ qkv,   // [B][197][3][768]
                 const float* __restrict__ addmask, // [B][197] or null
                 bf16_t* __restrict__ outp)          // [B][197][768]
{
    constexpr int KP = 232;  // padded key stride (>=224, 16B-multiple rows)
    __shared__ __align__(16) bf16_t Vt[64 * KP];       // Vt[hd][key]
    __shared__ __align__(16) bf16_t Ps[4][16 * KP];    // per-wave P[q][key]
    const int b = blockIdx.z, h = blockIdx.y, qt = blockIdx.x;
    const int tid = threadIdx.x, wave = tid >> 6, lane = tid & 63;
    const int quad = lane >> 4, l16 = lane & 15;

    // stage V^T (zero-padded keys 197..223)
    {
        int d = tid & 63, ng = tid >> 6;
        for (int n = ng; n < 224; n += 4) {
            bf16_t v = (bf16_t)0.f;
            if (n < 197)
                v = qkv[(((size_t)b * NTOK + n) * 3 + 2) * DMODEL + h * HDIM + d];
            Vt[d * KP + n] = v;
        }
    }
    __syncthreads();

    // Q fragments straight from global (A-op: m=lane&15, k=quad*8+j)
    const int qbase = qt * 64 + wave * 16;
    const int qrow = qbase + l16;
    const int qc = qrow < 196 ? qrow : 196;
    bf16x8 aq[2];
#pragma unroll
    for (int t = 0; t < 2; ++t)
        aq[t] = *reinterpret_cast<const bf16x8*>(
            qkv + (((size_t)b * NTOK + qc) * 3 + 0) * DMODEL + h * HDIM + t * 32 + quad * 8);

    // scores: 13 key-tiles of 16
    float sreg[13][4];
#pragma unroll
    for (int kt = 0; kt < 13; ++kt) {
        int key = kt * 16 + l16;
        int kc = key < 196 ? key : 196;
        const bf16_t* kb = qkv + (((size_t)b * NTOK + kc) * 3 + 1) * DMODEL + h * HDIM;
        bf16x8 kf0 = *reinterpret_cast<const bf16x8*>(kb + quad * 8);
        bf16x8 kf1 = *reinterpret_cast<const bf16x8*>(kb + 32 + quad * 8);
        f32x4 s = {0.f, 0.f, 0.f, 0.f};
        s = mfma16(aq[0], kf0, s);
        s = mfma16(aq[1], kf1, s);
        float am = addmask ? addmask[b * NTOK + kc] : 0.f;
        bool kvalid = key < 197;
#pragma unroll
        for (int r = 0; r < 4; ++r)
            sreg[kt][r] = kvalid ? (s[r] * ATT_SCALE + am) : -1e30f;
    }

    // softmax rows (row = quad*4+r, spread over the 16 lanes of the quad)
    float psum[4];
#pragma unroll
    for (int r = 0; r < 4; ++r) {
        float mx = -1e30f;
#pragma unroll
        for (int kt = 0; kt < 13; ++kt) mx = fmaxf(mx, sreg[kt][r]);
#pragma unroll
        for (int d = 1; d < 16; d <<= 1) mx = fmaxf(mx, __shfl_xor(mx, d, 64));
        float sum = 0.f;
#pragma unroll
        for (int kt = 0; kt < 13; ++kt) {
            float p = expf(sreg[kt][r] - mx);
            sreg[kt][r] = p;
            sum += p;
        }
#pragma unroll
        for (int d = 1; d < 16; d <<= 1) sum += __shfl_xor(sum, d, 64);
        psum[r] = sum;
    }

    // write P to LDS (C-layout -> A-layout transform), zero-pad cols 208..223
#pragma unroll
    for (int kt = 0; kt < 13; ++kt)
#pragma unroll
        for (int r = 0; r < 4; ++r)
            Ps[wave][(quad * 4 + r) * KP + kt * 16 + l16] = (bf16_t)sreg[kt][r];
    {
        int rr = lane & 15, c0 = 208 + (lane >> 4) * 4;
#pragma unroll
        for (int i = 0; i < 4; ++i) Ps[wave][rr * KP + c0 + i] = (bf16_t)0.f;
    }
    __syncthreads();   // P-write -> PV-read ordering

    // O = P @ V  (7 K-steps of 32 keys)
    f32x4 o[4];
#pragma unroll
    for (int j = 0; j < 4; ++j) o[j] = (f32x4){0.f, 0.f, 0.f, 0.f};
#pragma unroll
    for (int ks = 0; ks < 7; ++ks) {
        bf16x8 ap = *reinterpret_cast<const bf16x8*>(&Ps[wave][l16 * KP + ks * 32 + quad * 8]);
#pragma unroll
        for (int j = 0; j < 4; ++j) {
            bf16x8 vf = *reinterpret_cast<const bf16x8*>(&Vt[(j * 16 + l16) * KP + ks * 32 + quad * 8]);
            o[j] = mfma16(ap, vf, o[j]);
        }
    }

    // normalize + store
#pragma unroll
    for (int r = 0; r < 4; ++r) {
        int q = qbase + quad * 4 + r;
        if (q < 197) {
            float rs = 1.f / fmaxf(psum[r], 1e-20f);
#pragma unroll
            for (int j = 0; j < 4; ++j)
                outp[((size_t)b * NTOK + q) * DMODEL + h * HDIM + j * 16 + l16] =
                    (bf16_t)(o[j][r] * rs);
        }
    }
}

// --------------------------- small kernels ---------------------------------
__global__ __launch_bounds__(256)
void transpose_f32(const float* __restrict__ src, bf16_t* __restrict__ dst, int K, int N)
{
    __shared__ bf16_t tile[64][65];
    const size_t ls = (size_t)K * N * blockIdx.z;
    int k0 = blockIdx.y * 64, n0 = blockIdx.x * 64;
    int c = threadIdx.x & 63, r0 = threadIdx.x >> 6;
#pragma unroll
    for (int i = 0; i < 16; ++i) {
        int r = r0 + i * 4;
        tile[r][c] = (k0 + r < K && n0 + c < N)
                   ? (bf16_t)src[ls + (size_t)(k0 + r) * N + n0 + c] : (bf16_t)0.f;
    }
    __syncthreads();
#pragma unroll
    for (int i = 0; i < 16; ++i) {
        int r = r0 + i * 4;  // n-dim
        if (n0 + r < N && k0 + c < K) dst[ls + (size_t)(n0 + r) * K + k0 + c] = tile[c][r];
    }
}

__global__ void cvt_f32_bf16(const float* __restrict__ src, bf16_t* __restrict__ dst, int n)
{
    int i = blockIdx.x * 256 + threadIdx.x;
    if (i < n) dst[i] = (bf16_t)src[i];
}

__global__ void im2col_kernel(const float* __restrict__ img, bf16_t* __restrict__ Ap)
{
    int idx = blockIdx.x * 256 + threadIdx.x;
    if (idx >= PROWS * 768) return;
    int col = idx % 768, row = idx / 768;
    int b = row / 196, t = row % 196;
    int gi = t / 14, gj = t % 14;
    int c = col >> 8, rr = col & 255, p = rr >> 4, q = rr & 15;
    Ap[idx] = (bf16_t)img[(((size_t)b * 3 + c) * 224 + gi * 16 + p) * 224 + gj * 16 + q];
}

__global__ void assemble_x(const float* __restrict__ patch, const float* __restrict__ cls,
                           const float* __restrict__ pos, float* __restrict__ X)
{
    int idx = blockIdx.x * 256 + threadIdx.x;
    if (idx >= MROWS * DMODEL) return;
    int d = idx % DMODEL, rest = idx / DMODEL;
    int n = rest % NTOK, b = rest / NTOK;
    float v;
    if (n == 0) v = cls[d] + pos[d];
    else        v = patch[((size_t)b * 196 + (n - 1)) * DMODEL + d] + pos[(size_t)n * DMODEL + d];
    X[idx] = v;
}

// ---- gate path (fp32 end-to-end; top-k ranks must match np exactly) -------
// Fused: logits[m] = dot(gelu(A[m]@W1 + b1), w2) + b2, all fp32.
// 16 rows/block (M=6304=394*16, no guards), 256 threads.
__global__ __launch_bounds__(256)
void gate_fused_f32(const float* __restrict__ A, const float* __restrict__ W1,
                    const float* __restrict__ b1, const float* __restrict__ w2,
                    const float* __restrict__ b2, float* __restrict__ logits)
{
    __shared__ __align__(16) float As[16][64];
    __shared__ __align__(16) float Ws[64][128];
    const int tid = threadIdx.x;
    const int m0 = blockIdx.x * 16;
    const int tx = tid & 31;       // col group: cols tx*4..tx*4+3
    const int rg = tid >> 5;       // 0..7 -> rows rg*2, rg*2+1
    f32x4 acc0 = {0.f, 0.f, 0.f, 0.f};
    f32x4 acc1 = {0.f, 0.f, 0.f, 0.f};
    for (int k0 = 0; k0 < 768; k0 += 64) {
        __syncthreads();
        {   // stage A-tile: 1024 floats = 256 float4 (1/thread)
            int idx = tid * 4;
            int r = idx >> 6, c = idx & 63;
            *reinterpret_cast<f32x4*>(&As[r][c]) =
                *reinterpret_cast<const f32x4*>(&A[(size_t)(m0 + r) * 768 + k0 + c]);
        }
#pragma unroll
        for (int i = 0; i < 8; ++i) {  // stage W-tile: 8192 floats = 8 float4/thread
            int idx = (tid + i * 256) * 4;
            int r = idx >> 7, c = idx & 127;
            *reinterpret_cast<f32x4*>(&Ws[r][c]) =
                *reinterpret_cast<const f32x4*>(&W1[(size_t)(k0 + r) * 128 + c]);
        }
        __syncthreads();
#pragma unroll
        for (int kk = 0; kk < 64; ++kk) {
            float a0 = As[rg * 2 + 0][kk];   // broadcast (2 addrs/wave: free)
            float a1 = As[rg * 2 + 1][kk];
            f32x4 w = *reinterpret_cast<const f32x4*>(&Ws[kk][tx * 4]);  // b128, conflict-free
#pragma unroll
            for (int j = 0; j < 4; ++j) {
                acc0[j] += a0 * w[j];
                acc1[j] += a1 * w[j];
            }
        }
    }
    // epilogue: bias + gelu + dot(w2), reduce across the 32 tx lanes
    float s0 = 0.f, s1 = 0.f;
#pragma unroll
    for (int j = 0; j < 4; ++j) {
        int c = tx * 4 + j;
        float bj = b1[c], wj = w2[c];
        float v0 = acc0[j] + bj;
        float v1 = acc1[j] + bj;
        s0 += 0.5f * v0 * (1.f + erff(v0 * 0.70710678118f)) * wj;
        s1 += 0.5f * v1 * (1.f + erff(v1 * 0.70710678118f)) * wj;
    }
#pragma unroll
    for (int d = 1; d < 32; d <<= 1) {
        s0 += __shfl_xor(s0, d, 64);
        s1 += __shfl_xor(s1, d, 64);
    }
    if (tx == 0) {
        logits[m0 + rg * 2 + 0] = s0 + b2[0];
        logits[m0 + rg * 2 + 1] = s1 + b2[0];
    }
}

// exact top-118 of logits[b,1:197] by rank counting (lax.top_k tie-break: lower index)
__global__ __launch_bounds__(256)
void topk_kernel(const float* __restrict__ logits, float* __restrict__ maskm,
                 float* __restrict__ addm)
{
    __shared__ float ls[196];
    int b = blockIdx.x, t = threadIdx.x;
    if (t < 196) ls[t] = logits[b * NTOK + 1 + t];
    __syncthreads();
    if (t < 196) {
        float li = ls[t];
        int cnt = 0;
        for (int j = 0; j < 196; ++j) {
            float lj = ls[j];
            cnt += (lj > li) || (lj == li && j < t);
        }
        bool sel = cnt < KTOP;
        maskm[b * NTOK + 1 + t] = sel ? 1.f : 0.f;
        addm[b * NTOK + 1 + t]  = sel ? 0.f : LOGEPS;
    }
    if (t == 0) { maskm[b * NTOK] = 1.f; addm[b * NTOK] = 0.f; }
}

__global__ void fill_sentinel(float* out, int n)
{
    int i = blockIdx.x * 256 + threadIdx.x;
    if (i < n) out[i] = 12345.0f;
}

// ------------------------------- host --------------------------------------
static void launch_gemm(int mode, const bf16_t* A, const bf16_t* Wt, const float* bias,
                        void* C, float* resid, const float* rowmask,
                        int M, int N, int K, int ldc, hipStream_t s)
{
    dim3 grid((N + 127) / 128, (M + 127) / 128);
    dim3 blk(256);
    switch (mode) {
    case EP_BF16:    gemm_bf16<EP_BF16><<<grid, blk, 0, s>>>(A, Wt, bias, C, resid, rowmask, M, N, K, ldc); break;
    case EP_GELU:    gemm_bf16<EP_GELU><<<grid, blk, 0, s>>>(A, Wt, bias, C, resid, rowmask, M, N, K, ldc); break;
    case EP_RES:     gemm_bf16<EP_RES><<<grid, blk, 0, s>>>(A, Wt, bias, C, resid, rowmask, M, N, K, ldc); break;
    case EP_RESMASK: gemm_bf16<EP_RESMASK><<<grid, blk, 0, s>>>(A, Wt, bias, C, resid, rowmask, M, N, K, ldc); break;
    case EP_F32:     gemm_bf16<EP_F32><<<grid, blk, 0, s>>>(A, Wt, bias, C, resid, rowmask, M, N, K, ldc); break;
    }
}

extern "C" void kernel_launch(void* const* d_in, const int* in_sizes, int n_in,
                              void* d_out, int out_size, void* d_ws, size_t ws_size,
                              hipStream_t stream)
{
    (void)in_sizes; (void)n_in;
    const float* images   = (const float*)d_in[0];
    const float* patch_w  = (const float*)d_in[1];
    const float* patch_b  = (const float*)d_in[2];
    const float* cls_tok  = (const float*)d_in[3];
    const float* pos_emb  = (const float*)d_in[4];
    const float* w_ln1_g  = (const float*)d_in[5];
    const float* w_ln1_b  = (const float*)d_in[6];
    const float* w_qkv_w  = (const float*)d_in[7];
    const float* w_qkv_b  = (const float*)d_in[8];
    const float* w_proj_w = (const float*)d_in[9];
    const float* w_proj_b = (const float*)d_in[10];
    const float* w_ln2_g  = (const float*)d_in[11];
    const float* w_ln2_b  = (const float*)d_in[12];
    const float* w_fc1_w  = (const float*)d_in[13];
    const float* w_fc1_b  = (const float*)d_in[14];
    const float* w_fc2_w  = (const float*)d_in[15];
    const float* w_fc2_b  = (const float*)d_in[16];
    const float* d_ln1_g  = (const float*)d_in[17];
    const float* d_ln1_b  = (const float*)d_in[18];
    const float* d_qkv_w  = (const float*)d_in[19];
    const float* d_qkv_b  = (const float*)d_in[20];
    const float* d_proj_w = (const float*)d_in[21];
    const float* d_proj_b = (const float*)d_in[22];
    const float* d_ln2_g  = (const float*)d_in[23];
    const float* d_ln2_b  = (const float*)d_in[24];
    const float* d_fc1_w  = (const float*)d_in[25];
    const float* d_fc1_b  = (const float*)d_in[26];
    const float* d_fc2_w  = (const float*)d_in[27];
    const float* d_fc2_b  = (const float*)d_in[28];
    const float* d_gln_g  = (const float*)d_in[29];
    const float* d_gln_b  = (const float*)d_in[30];
    const float* d_gw1    = (const float*)d_in[31];
    const float* d_gb1    = (const float*)d_in[32];
    const float* d_gw2    = (const float*)d_in[33];
    const float* d_gb2    = (const float*)d_in[34];
    const float* norm_g   = (const float*)d_in[35];
    const float* norm_b   = (const float*)d_in[36];
    const float* head_w   = (const float*)d_in[37];
    const float* head_b   = (const float*)d_in[38];

    // workspace layout
    char* wp = (char*)d_ws;
    auto alloc = [&](size_t bytes) -> char* {
        char* p = wp; wp += (bytes + 255) & ~(size_t)255; return p;
    };
    bf16_t* wtqkv  = (bf16_t*)alloc((size_t)NLAYER * 2304 * 768 * 2);
    bf16_t* wtproj = (bf16_t*)alloc((size_t)NLAYER * 768 * 768 * 2);
    bf16_t* wtfc1  = (bf16_t*)alloc((size_t)NLAYER * 3072 * 768 * 2);
    bf16_t* wtfc2  = (bf16_t*)alloc((size_t)NLAYER * 768 * 3072 * 2);
    bf16_t* wthead = (bf16_t*)alloc((size_t)1024 * 768 * 2);
    bf16_t* pwbf   = (bf16_t*)alloc((size_t)768 * 768 * 2);
    float*  x      = (float*)alloc((size_t)MROWS * DMODEL * 4);
    bf16_t* h      = (bf16_t*)alloc((size_t)MROWS * DMODEL * 2);
    float*  hgate  = (float*)alloc((size_t)MROWS * DMODEL * 4);
    bf16_t* hcls   = (bf16_t*)alloc((size_t)NB * DMODEL * 2);
    bf16_t* qkvb   = (bf16_t*)alloc((size_t)MROWS * 2304 * 2);
    bf16_t* attno  = (bf16_t*)alloc((size_t)MROWS * DMODEL * 2);
    bf16_t* hid    = (bf16_t*)alloc((size_t)MROWS * HIDN * 2);
    float*  logits = (float*)alloc((size_t)MROWS * 4);
    float*  maskm  = (float*)alloc((size_t)MROWS * 4);
    float*  addm   = (float*)alloc((size_t)MROWS * 4);
    size_t used = (size_t)(wp - (char*)d_ws);
    if (used > ws_size) {  // diagnostic: distinctive absmax if ws is too small
        fill_sentinel<<<(out_size + 255) / 256, 256, 0, stream>>>((float*)d_out, out_size);
        return;
    }
    // patch scratch aliases hid (patch phase precedes any MLP use)
    bf16_t* Ap = hid;                                    // [6272][768] bf16
    float* patchout = (float*)((char*)hid + (size_t)PROWS * 768 * 2); // [6272][768] f32

    // ---- weight pre-transpose ([K][N] -> [N][K] bf16) ----
    transpose_f32<<<dim3(36, 12, 2),  256, 0, stream>>>(w_qkv_w,  wtqkv,                      768, 2304);
    transpose_f32<<<dim3(36, 12, 10), 256, 0, stream>>>(d_qkv_w,  wtqkv + (size_t)2*2304*768, 768, 2304);
    transpose_f32<<<dim3(12, 12, 2),  256, 0, stream>>>(w_proj_w, wtproj,                     768, 768);
    transpose_f32<<<dim3(12, 12, 10), 256, 0, stream>>>(d_proj_w, wtproj + (size_t)2*768*768, 768, 768);
    transpose_f32<<<dim3(48, 12, 2),  256, 0, stream>>>(w_fc1_w,  wtfc1,                      768, 3072);
    transpose_f32<<<dim3(48, 12, 10), 256, 0, stream>>>(d_fc1_w,  wtfc1 + (size_t)2*3072*768, 768, 3072);
    transpose_f32<<<dim3(12, 48, 2),  256, 0, stream>>>(w_fc2_w,  wtfc2,                      3072, 768);
    transpose_f32<<<dim3(12, 48, 10), 256, 0, stream>>>(d_fc2_w,  wtfc2 + (size_t)2*768*3072, 3072, 768);
    transpose_f32<<<dim3(16, 12, 1),  256, 0, stream>>>(head_w,   wthead,                     768, 1000);
    cvt_f32_bf16<<<(768 * 768 + 255) / 256, 256, 0, stream>>>(patch_w, pwbf, 768 * 768);

    // ---- patch embed + assemble ----
    im2col_kernel<<<(PROWS * 768 + 255) / 256, 256, 0, stream>>>(images, Ap);
    launch_gemm(EP_F32, Ap, pwbf, patch_b, patchout, nullptr, nullptr,
                PROWS, 768, 768, 768, stream);
    assemble_x<<<(MROWS * DMODEL + 255) / 256, 256, 0, stream>>>(patchout, cls_tok, pos_emb, x);

    // ---- transformer layers ----
    for (int L = 0; L < NLAYER; ++L) {
        bool warm = (L < 2);
        int li = warm ? L : (L - 2);
        const float* ln1g = warm ? w_ln1_g + li*768 : d_ln1_g + li*768;
        const float* ln1b = warm ? w_ln1_b + li*768 : d_ln1_b + li*768;
        const float* ln2g = warm ? w_ln2_g + li*768 : d_ln2_g + li*768;
        const float* ln2b = warm ? w_ln2_b + li*768 : d_ln2_b + li*768;
        const float* qkvbias  = warm ? w_qkv_b + li*2304 : d_qkv_b + li*2304;
        const float* projbias = warm ? w_proj_b + li*768 : d_proj_b + li*768;
        const float* fc1bias  = warm ? w_fc1_b + (size_t)li*3072 : d_fc1_b + (size_t)li*3072;
        const float* fc2bias  = warm ? w_fc2_b + li*768 : d_fc2_b + li*768;
        const bf16_t* Wq = wtqkv + (size_t)L * 2304 * 768;
        const bf16_t* Wp = wtproj + (size_t)L * 768 * 768;
        const bf16_t* W1 = wtfc1 + (size_t)L * 3072 * 768;
        const bf16_t* W2 = wtfc2 + (size_t)L * 768 * 3072;

        if (!warm) {
            // gate: LN -> fused fc1+gelu+dot -> top-118 mask   (all fp32)
            ln_kernel<float><<<MROWS, 256, 0, stream>>>(x, d_gln_g + li*768, d_gln_b + li*768, hgate, 1);
            gate_fused_f32<<<MROWS / 16, 256, 0, stream>>>(
                hgate, d_gw1 + (size_t)li*768*128, d_gb1 + li*128,
                d_gw2 + (size_t)li*128, d_gb2 + li, logits);
            topk_kernel<<<NB, 256, 0, stream>>>(logits, maskm, addm);
        }
        // attention
        ln_kernel<bf16_t><<<MROWS, 256, 0, stream>>>(x, ln1g, ln1b, h, 1);
        launch_gemm(EP_BF16, h, Wq, qkvbias, qkvb, nullptr, nullptr,
                    MROWS, 2304, 768, 2304, stream);
        attn_kernel<<<dim3(4, NHEAD, NB), 256, 0, stream>>>(qkvb, warm ? nullptr : addm, attno);
        launch_gemm(EP_RES, attno, Wp, projbias, nullptr, x, nullptr,
                    MROWS, 768, 768, 768, stream);
        // MLP
        ln_kernel<bf16_t><<<MROWS, 256, 0, stream>>>(x, ln2g, ln2b, h, 1);
        launch_gemm(EP_GELU, h, W1, fc1bias, hid, nullptr, nullptr,
                    MROWS, 3072, 768, 3072, stream);
        if (warm)
            launch_gemm(EP_RES, hid, W2, fc2bias, nullptr, x, nullptr,
                        MROWS, 768, 3072, 768, stream);
        else
            launch_gemm(EP_RESMASK, hid, W2, fc2bias, nullptr, x, maskm,
                        MROWS, 768, 3072, 768, stream);
    }

    // ---- final LN (cls rows only) + head -> fp32 d_out ----
    ln_kernel<bf16_t><<<NB, 256, 0, stream>>>(x, norm_g, norm_b, hcls, NTOK);
    launch_gemm(EP_F32, hcls, wthead, head_b, d_out, nullptr, nullptr,
                NB, 1000, 768, 1000, stream);
}

// Round 4
// 5119.847 us; speedup vs baseline: 1.2991x; 1.0517x over previous
//
#include <hip/hip_runtime.h>
#include <hip/hip_bf16.h>
#include <math.h>

// ---------------------------------------------------------------------------
// MaskedViT forward. R8: R7 (5384 us) + counted-vmcnt GEMM pipeline (T4):
// never drain vmcnt(0) in the K-loop. Per iter: s_waitcnt vmcnt(4) (tile kt
// done, tile kt+1 in flight) + raw s_barrier -> ds_read frags -> lgkmcnt(0)
// + s_barrier (buffer safe) -> stage tile kt+2 -> MFMA. Loads get a 2-iter
// latency budget. Rationale: R7 post-mortem showed __syncthreads' vmcnt(0)
// drain waits for the just-issued prefetch (fc2 ~1290 cyc/iter vs ~900 load
// latency); m218 measured counted-vs-drain0 = +38-73%.
// ---------------------------------------------------------------------------

typedef __bf16 bf16_t;
typedef __attribute__((ext_vector_type(8))) __bf16 bf16x8;
typedef __attribute__((ext_vector_type(4))) float f32x4;

#define DI __device__ __forceinline__

constexpr int NB     = 32;
constexpr int NTOK   = 197;
constexpr int DMODEL = 768;
constexpr int NHEAD  = 12;
constexpr int HDIM   = 64;
constexpr int HIDN   = 3072;
constexpr int GHID   = 128;
constexpr int MROWS  = NB * NTOK;   // 6304
constexpr int PROWS  = NB * 196;    // 6272
constexpr int NLAYER = 12;          // 2 warm + 10 dyn
constexpr int KTOP   = 118;
constexpr float ATT_SCALE = 0.125f;           // HD^-0.5
constexpr float LNEPS  = 1e-5f;
constexpr float LOGEPS = -13.815510558f;      // log(1e-6)

DI f32x4 mfma16(bf16x8 a, bf16x8 b, f32x4 c) {
    return __builtin_amdgcn_mfma_f32_16x16x32_bf16(a, b, c, 0, 0, 0);
}

// async global->LDS, 16B per lane. LDS dest must be wave-uniform base;
// HW writes lane's 16B at base + lane*16.
DI void gld_lds16(const void* g, void* l) {
    __builtin_amdgcn_global_load_lds(
        (__attribute__((address_space(1))) void*)(g),
        (__attribute__((address_space(3))) void*)(l), 16, 0, 0);
}

// ------------------------------- GEMM --------------------------------------
// C[M,N] = epilogue(A[M,K] @ Wt[N,K]^T + bias[N]); A,Wt bf16, acc fp32.
// 128x128 tile, BK=32, 4 waves in 2x2, each wave 64x64 (4x4 MFMA frags).
// Counted-vmcnt double-buffer: 2 K-tiles of loads in flight, per-wave
// vmcnt(4) + raw s_barrier publishes the older tile. OOB rows CLAMPED.
enum { EP_BF16 = 0, EP_GELU = 1, EP_RES = 2, EP_RESMASK = 3, EP_F32 = 4 };

template<int MODE>
__global__ __launch_bounds__(256)
void gemm_bf16(const bf16_t* __restrict__ A, const bf16_t* __restrict__ Wt,
               const float* __restrict__ bias, void* __restrict__ Cout,
               float* __restrict__ resid, const float* __restrict__ rowmask,
               int M, int N, int K, int ldc)
{
    __shared__ __align__(16) bf16_t As[2][128 * 32];
    __shared__ __align__(16) bf16_t Bs[2][128 * 32];
    const int tid  = threadIdx.x;
    const int lane = tid & 63;
    const int wave = tid >> 6;
    const int wm = wave >> 1, wn = wave & 1;
    const int quad = lane >> 4, l16 = lane & 15;
    const int m0 = blockIdx.y * 128;
    const int n0 = blockIdx.x * 128;

    f32x4 zero4 = {0.f, 0.f, 0.f, 0.f};
    f32x4 acc[4][4];
#pragma unroll
    for (int i = 0; i < 4; ++i)
#pragma unroll
        for (int j = 0; j < 4; ++j) acc[i][j] = zero4;

    // per-lane global source rows (clamped) and wave-uniform LDS offsets.
    const int rh  = tid >> 2;              // 0..63
    const int seg = tid & 3;               // 0..3 (8 bf16 each)
    const int rA0 = min(m0 + rh,      M - 1);
    const int rA1 = min(m0 + 64 + rh, M - 1);
    const int rB0 = min(n0 + rh,      N - 1);
    const int rB1 = min(n0 + 64 + rh, N - 1);
    const bf16_t* pA0 = A  + (size_t)rA0 * K + seg * 8;
    const bf16_t* pA1 = A  + (size_t)rA1 * K + seg * 8;
    const bf16_t* pB0 = Wt + (size_t)rB0 * K + seg * 8;
    const bf16_t* pB1 = Wt + (size_t)rB1 * K + seg * 8;
    const int lofs0 = wave * 512;          // within a buffer
    const int lofs1 = 2048 + wave * 512;

    auto stage = [&](int kt2, int buf) {   // 4 loads/wave, FIFO group
        const int kb = kt2 << 5;
        gld_lds16(pA0 + kb, As[buf] + lofs0);
        gld_lds16(pA1 + kb, As[buf] + lofs1);
        gld_lds16(pB0 + kb, Bs[buf] + lofs0);
        gld_lds16(pB1 + kb, Bs[buf] + lofs1);
    };

    const int nkt = K >> 5;   // >= 24 for all call sites (K >= 768)
    // prologue: stage K-tiles 0 and 1 (8 loads/wave in flight)
    stage(0, 0);
    stage(1, 1);

    for (int kt = 0; kt < nkt; ++kt) {
        const int cur = kt & 1;
        // wait: tile kt's 4 loads (oldest) done; tile kt+1's may stay in flight
        if (kt + 1 < nkt) asm volatile("s_waitcnt vmcnt(4)" ::: "memory");
        else              asm volatile("s_waitcnt vmcnt(0)" ::: "memory");
        __builtin_amdgcn_s_barrier();   // all waves' tile-kt loads landed

        bf16x8 af[4], bfr[4];
#pragma unroll
        for (int i = 0; i < 4; ++i)
            af[i] = *reinterpret_cast<const bf16x8*>(As[cur] + (wm * 64 + i * 16 + l16) * 32 + quad * 8);
#pragma unroll
        for (int j = 0; j < 4; ++j)
            bfr[j] = *reinterpret_cast<const bf16x8*>(Bs[cur] + (wn * 64 + j * 16 + l16) * 32 + quad * 8);

        asm volatile("s_waitcnt lgkmcnt(0)" ::: "memory");  // my LDS reads done
        __builtin_amdgcn_sched_barrier(0);
        __builtin_amdgcn_s_barrier();   // everyone's reads done -> buf reusable

        if (kt + 2 < nkt) stage(kt + 2, cur);   // overwrite buf[cur] for kt+2

#pragma unroll
        for (int i = 0; i < 4; ++i)
#pragma unroll
            for (int j = 0; j < 4; ++j)
                acc[i][j] = mfma16(af[i], bfr[j], acc[i][j]);
    }

    // epilogue: C/D layout col=lane&15, row=quad*4+reg
#pragma unroll
    for (int j = 0; j < 4; ++j) {
        int c = n0 + wn * 64 + j * 16 + l16;
        if (c >= N) continue;
        float bj = bias ? bias[c] : 0.f;
#pragma unroll
        for (int i = 0; i < 4; ++i) {
#pragma unroll
            for (int r = 0; r < 4; ++r) {
                int mr = m0 + wm * 64 + i * 16 + quad * 4 + r;
                if (mr >= M) continue;
                float v = acc[i][j][r] + bj;
                size_t off = (size_t)mr * ldc + c;
                if (MODE == EP_BF16) {
                    ((bf16_t*)Cout)[off] = (bf16_t)v;
                } else if (MODE == EP_GELU) {
                    float g = 0.5f * v * (1.f + erff(v * 0.70710678118f));
                    ((bf16_t*)Cout)[off] = (bf16_t)g;
                } else if (MODE == EP_F32) {
                    ((float*)Cout)[off] = v;
                } else if (MODE == EP_RES) {
                    resid[off] += v;
                } else { // EP_RESMASK
                    resid[off] += v * rowmask[mr];
                }
            }
        }
    }
}

// ------------------------------ LayerNorm ----------------------------------
DI float block_reduce_sum(float val, float* sh) {
#pragma unroll
    for (int off = 32; off; off >>= 1) val += __shfl_down(val, off, 64);
    __syncthreads();
    if ((threadIdx.x & 63) == 0) sh[threadIdx.x >> 6] = val;
    __syncthreads();
    return sh[0] + sh[1] + sh[2] + sh[3];
}

// in row = blockIdx.x * row_mul (fp32); OUT = bf16 or fp32
template<typename OUT>
__global__ __launch_bounds__(256)
void ln_kernel(const float* __restrict__ X, const float* __restrict__ g,
               const float* __restrict__ bta, OUT* __restrict__ H, int row_mul)
{
    __shared__ float sh[4];
    const int t = threadIdx.x;
    const float* xr = X + (size_t)blockIdx.x * row_mul * DMODEL;
    float v[3];
#pragma unroll
    for (int i = 0; i < 3; ++i) v[i] = xr[t + i * 256];
    float s = v[0] + v[1] + v[2];
    s = block_reduce_sum(s, sh);
    float mu = s * (1.f / DMODEL);
    float q = 0.f;
#pragma unroll
    for (int i = 0; i < 3; ++i) { float d = v[i] - mu; q += d * d; }
    q = block_reduce_sum(q, sh);
    float rstd = rsqrtf(q * (1.f / DMODEL) + LNEPS);
    OUT* hr = H + (size_t)blockIdx.x * DMODEL;
#pragma unroll
    for (int i = 0; i < 3; ++i) {
        int c = t + i * 256;
        hr[c] = (OUT)((v[i] - mu) * rstd * g[c] + bta[c]);
    }
}

// ------------------------------ Attention ----------------------------------
__global__ __launch_bounds__(256)
void attn_kernel(const bf16_t* __restrict__ qkv,   // [B][197][3][768]
                 const float* __restrict__ addmask, // [B][197] or null
                 bf16_t* __restrict__ outp)          // [B][197][768]
{
    constexpr int KP = 232;  // padded key stride (>=224, 16B-multiple rows)
    __shared__ __align__(16) bf16_t Vt[64 * KP];       // Vt[hd][key]
    __shared__ __align__(16) bf16_t Ps[4][16 * KP];    // per-wave P[q][key]
    const int b = blockIdx.z, h = blockIdx.y, qt = blockIdx.x;
    const int tid = threadIdx.x, wave = tid >> 6, lane = tid & 63;
    const int quad = lane >> 4, l16 = lane & 15;

    // stage V^T (zero-padded keys 197..223)
    {
        int d = tid & 63, ng = tid >> 6;
        for (int n = ng; n < 224; n += 4) {
            bf16_t v = (bf16_t)0.f;
            if (n < 197)
                v = qkv[(((size_t)b * NTOK + n) * 3 + 2) * DMODEL + h * HDIM + d];
            Vt[d * KP + n] = v;
        }
    }
    __syncthreads();

    // Q fragments straight from global (A-op: m=lane&15, k=quad*8+j)
    const int qbase = qt * 64 + wave * 16;
    const int qrow = qbase + l16;
    const int qc = qrow < 196 ? qrow : 196;
    bf16x8 aq[2];
#pragma unroll
    for (int t = 0; t < 2; ++t)
        aq[t] = *reinterpret_cast<const bf16x8*>(
            qkv + (((size_t)b * NTOK + qc) * 3 + 0) * DMODEL + h * HDIM + t * 32 + quad * 8);

    // scores: 13 key-tiles of 16
    float sreg[13][4];
#pragma unroll
    for (int kt = 0; kt < 13; ++kt) {
        int key = kt * 16 + l16;
        int kc = key < 196 ? key : 196;
        const bf16_t* kb = qkv + (((size_t)b * NTOK + kc) * 3 + 1) * DMODEL + h * HDIM;
        bf16x8 kf0 = *reinterpret_cast<const bf16x8*>(kb + quad * 8);
        bf16x8 kf1 = *reinterpret_cast<const bf16x8*>(kb + 32 + quad * 8);
        f32x4 s = {0.f, 0.f, 0.f, 0.f};
        s = mfma16(aq[0], kf0, s);
        s = mfma16(aq[1], kf1, s);
        float am = addmask ? addmask[b * NTOK + kc] : 0.f;
        bool kvalid = key < 197;
#pragma unroll
        for (int r = 0; r < 4; ++r)
            sreg[kt][r] = kvalid ? (s[r] * ATT_SCALE + am) : -1e30f;
    }

    // softmax rows (row = quad*4+r, spread over the 16 lanes of the quad)
    float psum[4];
#pragma unroll
    for (int r = 0; r < 4; ++r) {
        float mx = -1e30f;
#pragma unroll
        for (int kt = 0; kt < 13; ++kt) mx = fmaxf(mx, sreg[kt][r]);
#pragma unroll
        for (int d = 1; d < 16; d <<= 1) mx = fmaxf(mx, __shfl_xor(mx, d, 64));
        float sum = 0.f;
#pragma unroll
        for (int kt = 0; kt < 13; ++kt) {
            float p = expf(sreg[kt][r] - mx);
            sreg[kt][r] = p;
            sum += p;
        }
#pragma unroll
        for (int d = 1; d < 16; d <<= 1) sum += __shfl_xor(sum, d, 64);
        psum[r] = sum;
    }

    // write P to LDS (C-layout -> A-layout transform), zero-pad cols 208..223
#pragma unroll
    for (int kt = 0; kt < 13; ++kt)
#pragma unroll
        for (int r = 0; r < 4; ++r)
            Ps[wave][(quad * 4 + r) * KP + kt * 16 + l16] = (bf16_t)sreg[kt][r];
    {
        int rr = lane & 15, c0 = 208 + (lane >> 4) * 4;
#pragma unroll
        for (int i = 0; i < 4; ++i) Ps[wave][rr * KP + c0 + i] = (bf16_t)0.f;
    }
    __syncthreads();   // P-write -> PV-read ordering

    // O = P @ V  (7 K-steps of 32 keys)
    f32x4 o[4];
#pragma unroll
    for (int j = 0; j < 4; ++j) o[j] = (f32x4){0.f, 0.f, 0.f, 0.f};
#pragma unroll
    for (int ks = 0; ks < 7; ++ks) {
        bf16x8 ap = *reinterpret_cast<const bf16x8*>(&Ps[wave][l16 * KP + ks * 32 + quad * 8]);
#pragma unroll
        for (int j = 0; j < 4; ++j) {
            bf16x8 vf = *reinterpret_cast<const bf16x8*>(&Vt[(j * 16 + l16) * KP + ks * 32 + quad * 8]);
            o[j] = mfma16(ap, vf, o[j]);
        }
    }

    // normalize + store
#pragma unroll
    for (int r = 0; r < 4; ++r) {
        int q = qbase + quad * 4 + r;
        if (q < 197) {
            float rs = 1.f / fmaxf(psum[r], 1e-20f);
#pragma unroll
            for (int j = 0; j < 4; ++j)
                outp[((size_t)b * NTOK + q) * DMODEL + h * HDIM + j * 16 + l16] =
                    (bf16_t)(o[j][r] * rs);
        }
    }
}

// --------------------------- small kernels ---------------------------------
__global__ __launch_bounds__(256)
void transpose_f32(const float* __restrict__ src, bf16_t* __restrict__ dst, int K, int N)
{
    __shared__ bf16_t tile[64][65];
    const size_t ls = (size_t)K * N * blockIdx.z;
    int k0 = blockIdx.y * 64, n0 = blockIdx.x * 64;
    int c = threadIdx.x & 63, r0 = threadIdx.x >> 6;
#pragma unroll
    for (int i = 0; i < 16; ++i) {
        int r = r0 + i * 4;
        tile[r][c] = (k0 + r < K && n0 + c < N)
                   ? (bf16_t)src[ls + (size_t)(k0 + r) * N + n0 + c] : (bf16_t)0.f;
    }
    __syncthreads();
#pragma unroll
    for (int i = 0; i < 16; ++i) {
        int r = r0 + i * 4;  // n-dim
        if (n0 + r < N && k0 + c < K) dst[ls + (size_t)(n0 + r) * K + k0 + c] = tile[c][r];
    }
}

__global__ void cvt_f32_bf16(const float* __restrict__ src, bf16_t* __restrict__ dst, int n)
{
    int i = blockIdx.x * 256 + threadIdx.x;
    if (i < n) dst[i] = (bf16_t)src[i];
}

__global__ void im2col_kernel(const float* __restrict__ img, bf16_t* __restrict__ Ap)
{
    int idx = blockIdx.x * 256 + threadIdx.x;
    if (idx >= PROWS * 768) return;
    int col = idx % 768, row = idx / 768;
    int b = row / 196, t = row % 196;
    int gi = t / 14, gj = t % 14;
    int c = col >> 8, rr = col & 255, p = rr >> 4, q = rr & 15;
    Ap[idx] = (bf16_t)img[(((size_t)b * 3 + c) * 224 + gi * 16 + p) * 224 + gj * 16 + q];
}

__global__ void assemble_x(const float* __restrict__ patch, const float* __restrict__ cls,
                           const float* __restrict__ pos, float* __restrict__ X)
{
    int idx = blockIdx.x * 256 + threadIdx.x;
    if (idx >= MROWS * DMODEL) return;
    int d = idx % DMODEL, rest = idx / DMODEL;
    int n = rest % NTOK, b = rest / NTOK;
    float v;
    if (n == 0) v = cls[d] + pos[d];
    else        v = patch[((size_t)b * 196 + (n - 1)) * DMODEL + d] + pos[(size_t)n * DMODEL + d];
    X[idx] = v;
}

// ---- gate path (fp32 end-to-end; top-k ranks must match np exactly) -------
// Fused: logits[m] = dot(gelu(A[m]@W1 + b1), w2) + b2, all fp32.
// 16 rows/block (M=6304=394*16, no guards), 256 threads.
__global__ __launch_bounds__(256)
void gate_fused_f32(const float* __restrict__ A, const float* __restrict__ W1,
                    const float* __restrict__ b1, const float* __restrict__ w2,
                    const float* __restrict__ b2, float* __restrict__ logits)
{
    __shared__ __align__(16) float As[16][64];
    __shared__ __align__(16) float Ws[64][128];
    const int tid = threadIdx.x;
    const int m0 = blockIdx.x * 16;
    const int tx = tid & 31;       // col group: cols tx*4..tx*4+3
    const int rg = tid >> 5;       // 0..7 -> rows rg*2, rg*2+1
    f32x4 acc0 = {0.f, 0.f, 0.f, 0.f};
    f32x4 acc1 = {0.f, 0.f, 0.f, 0.f};
    for (int k0 = 0; k0 < 768; k0 += 64) {
        __syncthreads();
        {   // stage A-tile: 1024 floats = 256 float4 (1/thread)
            int idx = tid * 4;
            int r = idx >> 6, c = idx & 63;
            *reinterpret_cast<f32x4*>(&As[r][c]) =
                *reinterpret_cast<const f32x4*>(&A[(size_t)(m0 + r) * 768 + k0 + c]);
        }
#pragma unroll
        for (int i = 0; i < 8; ++i) {  // stage W-tile: 8192 floats = 8 float4/thread
            int idx = (tid + i * 256) * 4;
            int r = idx >> 7, c = idx & 127;
            *reinterpret_cast<f32x4*>(&Ws[r][c]) =
                *reinterpret_cast<const f32x4*>(&W1[(size_t)(k0 + r) * 128 + c]);
        }
        __syncthreads();
#pragma unroll
        for (int kk = 0; kk < 64; ++kk) {
            float a0 = As[rg * 2 + 0][kk];   // broadcast (2 addrs/wave: free)
            float a1 = As[rg * 2 + 1][kk];
            f32x4 w = *reinterpret_cast<const f32x4*>(&Ws[kk][tx * 4]);  // b128, conflict-free
#pragma unroll
            for (int j = 0; j < 4; ++j) {
                acc0[j] += a0 * w[j];
                acc1[j] += a1 * w[j];
            }
        }
    }
    // epilogue: bias + gelu + dot(w2), reduce across the 32 tx lanes
    float s0 = 0.f, s1 = 0.f;
#pragma unroll
    for (int j = 0; j < 4; ++j) {
        int c = tx * 4 + j;
        float bj = b1[c], wj = w2[c];
        float v0 = acc0[j] + bj;
        float v1 = acc1[j] + bj;
        s0 += 0.5f * v0 * (1.f + erff(v0 * 0.70710678118f)) * wj;
        s1 += 0.5f * v1 * (1.f + erff(v1 * 0.70710678118f)) * wj;
    }
#pragma unroll
    for (int d = 1; d < 32; d <<= 1) {
        s0 += __shfl_xor(s0, d, 64);
        s1 += __shfl_xor(s1, d, 64);
    }
    if (tx == 0) {
        logits[m0 + rg * 2 + 0] = s0 + b2[0];
        logits[m0 + rg * 2 + 1] = s1 + b2[0];
    }
}

// exact top-118 of logits[b,1:197] by rank counting (lax.top_k tie-break: lower index)
__global__ __launch_bounds__(256)
void topk_kernel(const float* __restrict__ logits, float* __restrict__ maskm,
                 float* __restrict__ addm)
{
    __shared__ float ls[196];
    int b = blockIdx.x, t = threadIdx.x;
    if (t < 196) ls[t] = logits[b * NTOK + 1 + t];
    __syncthreads();
    if (t < 196) {
        float li = ls[t];
        int cnt = 0;
        for (int j = 0; j < 196; ++j) {
            float lj = ls[j];
            cnt += (lj > li) || (lj == li && j < t);
        }
        bool sel = cnt < KTOP;
        maskm[b * NTOK + 1 + t] = sel ? 1.f : 0.f;
        addm[b * NTOK + 1 + t]  = sel ? 0.f : LOGEPS;
    }
    if (t == 0) { maskm[b * NTOK] = 1.f; addm[b * NTOK] = 0.f; }
}

__global__ void fill_sentinel(float* out, int n)
{
    int i = blockIdx.x * 256 + threadIdx.x;
    if (i < n) out[i] = 12345.0f;
}

// ------------------------------- host --------------------------------------
static void launch_gemm(int mode, const bf16_t* A, const bf16_t* Wt, const float* bias,
                        void* C, float* resid, const float* rowmask,
                        int M, int N, int K, int ldc, hipStream_t s)
{
    dim3 grid((N + 127) / 128, (M + 127) / 128);
    dim3 blk(256);
    switch (mode) {
    case EP_BF16:    gemm_bf16<EP_BF16><<<grid, blk, 0, s>>>(A, Wt, bias, C, resid, rowmask, M, N, K, ldc); break;
    case EP_GELU:    gemm_bf16<EP_GELU><<<grid, blk, 0, s>>>(A, Wt, bias, C, resid, rowmask, M, N, K, ldc); break;
    case EP_RES:     gemm_bf16<EP_RES><<<grid, blk, 0, s>>>(A, Wt, bias, C, resid, rowmask, M, N, K, ldc); break;
    case EP_RESMASK: gemm_bf16<EP_RESMASK><<<grid, blk, 0, s>>>(A, Wt, bias, C, resid, rowmask, M, N, K, ldc); break;
    case EP_F32:     gemm_bf16<EP_F32><<<grid, blk, 0, s>>>(A, Wt, bias, C, resid, rowmask, M, N, K, ldc); break;
    }
}

extern "C" void kernel_launch(void* const* d_in, const int* in_sizes, int n_in,
                              void* d_out, int out_size, void* d_ws, size_t ws_size,
                              hipStream_t stream)
{
    (void)in_sizes; (void)n_in;
    const float* images   = (const float*)d_in[0];
    const float* patch_w  = (const float*)d_in[1];
    const float* patch_b  = (const float*)d_in[2];
    const float* cls_tok  = (const float*)d_in[3];
    const float* pos_emb  = (const float*)d_in[4];
    const float* w_ln1_g  = (const float*)d_in[5];
    const float* w_ln1_b  = (const float*)d_in[6];
    const float* w_qkv_w  = (const float*)d_in[7];
    const float* w_qkv_b  = (const float*)d_in[8];
    const float* w_proj_w = (const float*)d_in[9];
    const float* w_proj_b = (const float*)d_in[10];
    const float* w_ln2_g  = (const float*)d_in[11];
    const float* w_ln2_b  = (const float*)d_in[12];
    const float* w_fc1_w  = (const float*)d_in[13];
    const float* w_fc1_b  = (const float*)d_in[14];
    const float* w_fc2_w  = (const float*)d_in[15];
    const float* w_fc2_b  = (const float*)d_in[16];
    const float* d_ln1_g  = (const float*)d_in[17];
    const float* d_ln1_b  = (const float*)d_in[18];
    const float* d_qkv_w  = (const float*)d_in[19];
    const float* d_qkv_b  = (const float*)d_in[20];
    const float* d_proj_w = (const float*)d_in[21];
    const float* d_proj_b = (const float*)d_in[22];
    const float* d_ln2_g  = (const float*)d_in[23];
    const float* d_ln2_b  = (const float*)d_in[24];
    const float* d_fc1_w  = (const float*)d_in[25];
    const float* d_fc1_b  = (const float*)d_in[26];
    const float* d_fc2_w  = (const float*)d_in[27];
    const float* d_fc2_b  = (const float*)d_in[28];
    const float* d_gln_g  = (const float*)d_in[29];
    const float* d_gln_b  = (const float*)d_in[30];
    const float* d_gw1    = (const float*)d_in[31];
    const float* d_gb1    = (const float*)d_in[32];
    const float* d_gw2    = (const float*)d_in[33];
    const float* d_gb2    = (const float*)d_in[34];
    const float* norm_g   = (const float*)d_in[35];
    const float* norm_b   = (const float*)d_in[36];
    const float* head_w   = (const float*)d_in[37];
    const float* head_b   = (const float*)d_in[38];

    // workspace layout
    char* wp = (char*)d_ws;
    auto alloc = [&](size_t bytes) -> char* {
        char* p = wp; wp += (bytes + 255) & ~(size_t)255; return p;
    };
    bf16_t* wtqkv  = (bf16_t*)alloc((size_t)NLAYER * 2304 * 768 * 2);
    bf16_t* wtproj = (bf16_t*)alloc((size_t)NLAYER * 768 * 768 * 2);
    bf16_t* wtfc1  = (bf16_t*)alloc((size_t)NLAYER * 3072 * 768 * 2);
    bf16_t* wtfc2  = (bf16_t*)alloc((size_t)NLAYER * 768 * 3072 * 2);
    bf16_t* wthead = (bf16_t*)alloc((size_t)1024 * 768 * 2);
    bf16_t* pwbf   = (bf16_t*)alloc((size_t)768 * 768 * 2);
    float*  x      = (float*)alloc((size_t)MROWS * DMODEL * 4);
    bf16_t* h      = (bf16_t*)alloc((size_t)MROWS * DMODEL * 2);
    float*  hgate  = (float*)alloc((size_t)MROWS * DMODEL * 4);
    bf16_t* hcls   = (bf16_t*)alloc((size_t)NB * DMODEL * 2);
    bf16_t* qkvb   = (bf16_t*)alloc((size_t)MROWS * 2304 * 2);
    bf16_t* attno  = (bf16_t*)alloc((size_t)MROWS * DMODEL * 2);
    bf16_t* hid    = (bf16_t*)alloc((size_t)MROWS * HIDN * 2);
    float*  logits = (float*)alloc((size_t)MROWS * 4);
    float*  maskm  = (float*)alloc((size_t)MROWS * 4);
    float*  addm   = (float*)alloc((size_t)MROWS * 4);
    size_t used = (size_t)(wp - (char*)d_ws);
    if (used > ws_size) {  // diagnostic: distinctive absmax if ws is too small
        fill_sentinel<<<(out_size + 255) / 256, 256, 0, stream>>>((float*)d_out, out_size);
        return;
    }
    // patch scratch aliases hid (patch phase precedes any MLP use)
    bf16_t* Ap = hid;                                    // [6272][768] bf16
    float* patchout = (float*)((char*)hid + (size_t)PROWS * 768 * 2); // [6272][768] f32

    // ---- weight pre-transpose ([K][N] -> [N][K] bf16) ----
    transpose_f32<<<dim3(36, 12, 2),  256, 0, stream>>>(w_qkv_w,  wtqkv,                      768, 2304);
    transpose_f32<<<dim3(36, 12, 10), 256, 0, stream>>>(d_qkv_w,  wtqkv + (size_t)2*2304*768, 768, 2304);
    transpose_f32<<<dim3(12, 12, 2),  256, 0, stream>>>(w_proj_w, wtproj,                     768, 768);
    transpose_f32<<<dim3(12, 12, 10), 256, 0, stream>>>(d_proj_w, wtproj + (size_t)2*768*768, 768, 768);
    transpose_f32<<<dim3(48, 12, 2),  256, 0, stream>>>(w_fc1_w,  wtfc1,                      768, 3072);
    transpose_f32<<<dim3(48, 12, 10), 256, 0, stream>>>(d_fc1_w,  wtfc1 + (size_t)2*3072*768, 768, 3072);
    transpose_f32<<<dim3(12, 48, 2),  256, 0, stream>>>(w_fc2_w,  wtfc2,                      3072, 768);
    transpose_f32<<<dim3(12, 48, 10), 256, 0, stream>>>(d_fc2_w,  wtfc2 + (size_t)2*768*3072, 3072, 768);
    transpose_f32<<<dim3(16, 12, 1),  256, 0, stream>>>(head_w,   wthead,                     768, 1000);
    cvt_f32_bf16<<<(768 * 768 + 255) / 256, 256, 0, stream>>>(patch_w, pwbf, 768 * 768);

    // ---- patch embed + assemble ----
    im2col_kernel<<<(PROWS * 768 + 255) / 256, 256, 0, stream>>>(images, Ap);
    launch_gemm(EP_F32, Ap, pwbf, patch_b, patchout, nullptr, nullptr,
                PROWS, 768, 768, 768, stream);
    assemble_x<<<(MROWS * DMODEL + 255) / 256, 256, 0, stream>>>(patchout, cls_tok, pos_emb, x);

    // ---- transformer layers ----
    for (int L = 0; L < NLAYER; ++L) {
        bool warm = (L < 2);
        int li = warm ? L : (L - 2);
        const float* ln1g = warm ? w_ln1_g + li*768 : d_ln1_g + li*768;
        const float* ln1b = warm ? w_ln1_b + li*768 : d_ln1_b + li*768;
        const float* ln2g = warm ? w_ln2_g + li*768 : d_ln2_g + li*768;
        const float* ln2b = warm ? w_ln2_b + li*768 : d_ln2_b + li*768;
        const float* qkvbias  = warm ? w_qkv_b + li*2304 : d_qkv_b + li*2304;
        const float* projbias = warm ? w_proj_b + li*768 : d_proj_b + li*768;
        const float* fc1bias  = warm ? w_fc1_b + (size_t)li*3072 : d_fc1_b + (size_t)li*3072;
        const float* fc2bias  = warm ? w_fc2_b + li*768 : d_fc2_b + li*768;
        const bf16_t* Wq = wtqkv + (size_t)L * 2304 * 768;
        const bf16_t* Wp = wtproj + (size_t)L * 768 * 768;
        const bf16_t* W1 = wtfc1 + (size_t)L * 3072 * 768;
        const bf16_t* W2 = wtfc2 + (size_t)L * 768 * 3072;

        if (!warm) {
            // gate: LN -> fused fc1+gelu+dot -> top-118 mask   (all fp32)
            ln_kernel<float><<<MROWS, 256, 0, stream>>>(x, d_gln_g + li*768, d_gln_b + li*768, hgate, 1);
            gate_fused_f32<<<MROWS / 16, 256, 0, stream>>>(
                hgate, d_gw1 + (size_t)li*768*128, d_gb1 + li*128,
                d_gw2 + (size_t)li*128, d_gb2 + li, logits);
            topk_kernel<<<NB, 256, 0, stream>>>(logits, maskm, addm);
        }
        // attention
        ln_kernel<bf16_t><<<MROWS, 256, 0, stream>>>(x, ln1g, ln1b, h, 1);
        launch_gemm(EP_BF16, h, Wq, qkvbias, qkvb, nullptr, nullptr,
                    MROWS, 2304, 768, 2304, stream);
        attn_kernel<<<dim3(4, NHEAD, NB), 256, 0, stream>>>(qkvb, warm ? nullptr : addm, attno);
        launch_gemm(EP_RES, attno, Wp, projbias, nullptr, x, nullptr,
                    MROWS, 768, 768, 768, stream);
        // MLP
        ln_kernel<bf16_t><<<MROWS, 256, 0, stream>>>(x, ln2g, ln2b, h, 1);
        launch_gemm(EP_GELU, h, W1, fc1bias, hid, nullptr, nullptr,
                    MROWS, 3072, 768, 3072, stream);
        if (warm)
            launch_gemm(EP_RES, hid, W2, fc2bias, nullptr, x, nullptr,
                        MROWS, 768, 3072, 768, stream);
        else
            launch_gemm(EP_RESMASK, hid, W2, fc2bias, nullptr, x, maskm,
                        MROWS, 768, 3072, 768, stream);
    }

    // ---- final LN (cls rows only) + head -> fp32 d_out ----
    ln_kernel<bf16_t><<<NB, 256, 0, stream>>>(x, norm_g, norm_b, hcls, NTOK);
    launch_gemm(EP_F32, hcls, wthead, head_b, d_out, nullptr, nullptr,
                NB, 1000, 768, 1000, stream);
}

// Round 5
// 4620.293 us; speedup vs baseline: 1.4396x; 1.1081x over previous
//
#include <hip/hip_runtime.h>
#include <hip/hip_bf16.h>
#include <math.h>

// ---------------------------------------------------------------------------
// MaskedViT forward. R9: R8 (5120 us) + EXACT masked-row MLP compaction:
// dyn-layer fc1/fc2 compute only the 119 selected rows/batch (x += v*m means
// masked rows are discarded). topk emits rowidx (rank-ordered compaction);
// fc1 gathers A-rows (free via per-lane global_load_lds src addrs), fc2
// scatters resid via rowidx with split-K=2 + atomicAdd (restores grid
// parallelism lost to compaction; bias added by kz==0 only).
// GEMM K-loop keeps R8's counted-vmcnt pipeline.
// ---------------------------------------------------------------------------

typedef __bf16 bf16_t;
typedef __attribute__((ext_vector_type(8))) __bf16 bf16x8;
typedef __attribute__((ext_vector_type(4))) float f32x4;

#define DI __device__ __forceinline__

constexpr int NB     = 32;
constexpr int NTOK   = 197;
constexpr int DMODEL = 768;
constexpr int NHEAD  = 12;
constexpr int HDIM   = 64;
constexpr int HIDN   = 3072;
constexpr int GHID   = 128;
constexpr int MROWS  = NB * NTOK;   // 6304
constexpr int PROWS  = NB * 196;    // 6272
constexpr int NSEL   = 119;         // cls + top-118
constexpr int MROWSC = NB * NSEL;   // 3808 compacted MLP rows
constexpr int NLAYER = 12;          // 2 warm + 10 dyn
constexpr int KTOP   = 118;
constexpr float ATT_SCALE = 0.125f;           // HD^-0.5
constexpr float LNEPS  = 1e-5f;
constexpr float LOGEPS = -13.815510558f;      // log(1e-6)

DI f32x4 mfma16(bf16x8 a, bf16x8 b, f32x4 c) {
    return __builtin_amdgcn_mfma_f32_16x16x32_bf16(a, b, c, 0, 0, 0);
}

// async global->LDS, 16B per lane. LDS dest must be wave-uniform base;
// HW writes lane's 16B at base + lane*16.
DI void gld_lds16(const void* g, void* l) {
    __builtin_amdgcn_global_load_lds(
        (__attribute__((address_space(1))) void*)(g),
        (__attribute__((address_space(3))) void*)(l), 16, 0, 0);
}

// ------------------------------- GEMM --------------------------------------
// C[M,N] = epilogue(A[M,K] @ Wt[N,K]^T + bias[N]); A,Wt bf16, acc fp32.
// 128x128 tile, BK=32, 4 waves 2x2, wave = 64x64 (4x4 MFMA frags).
// Counted-vmcnt double-buffer (R8). GA: gather A rows via rowidx.
// SC: scatter output rows via rowidx. AT: atomicAdd epilogue (split-K,
// koff = blockIdx.z*klen; bias only by z==0). OOB rows CLAMPED.
enum { EP_BF16 = 0, EP_GELU = 1, EP_RES = 2, EP_F32 = 4 };

template<int MODE, bool GA, bool SC, bool AT>
__global__ __launch_bounds__(256)
void gemm_bf16(const bf16_t* __restrict__ A, const bf16_t* __restrict__ Wt,
               const float* __restrict__ bias, void* __restrict__ Cout,
               float* __restrict__ resid, const int* __restrict__ rowidx,
               int M, int N, int K, int ldc, int klen)
{
    __shared__ __align__(16) bf16_t As[2][128 * 32];
    __shared__ __align__(16) bf16_t Bs[2][128 * 32];
    const int tid  = threadIdx.x;
    const int lane = tid & 63;
    const int wave = tid >> 6;
    const int wm = wave >> 1, wn = wave & 1;
    const int quad = lane >> 4, l16 = lane & 15;
    const int m0 = blockIdx.y * 128;
    const int n0 = blockIdx.x * 128;
    const int koff = AT ? blockIdx.z * klen : 0;

    f32x4 zero4 = {0.f, 0.f, 0.f, 0.f};
    f32x4 acc[4][4];
#pragma unroll
    for (int i = 0; i < 4; ++i)
#pragma unroll
        for (int j = 0; j < 4; ++j) acc[i][j] = zero4;

    // per-lane global source rows (clamped; optionally gathered)
    const int rh  = tid >> 2;              // 0..63
    const int seg = tid & 3;               // 0..3 (8 bf16 each)
    int cA0 = min(m0 + rh,      M - 1);
    int cA1 = min(m0 + 64 + rh, M - 1);
    const int rA0 = GA ? rowidx[cA0] : cA0;
    const int rA1 = GA ? rowidx[cA1] : cA1;
    const int rB0 = min(n0 + rh,      N - 1);
    const int rB1 = min(n0 + 64 + rh, N - 1);
    const bf16_t* pA0 = A  + (size_t)rA0 * K + koff + seg * 8;
    const bf16_t* pA1 = A  + (size_t)rA1 * K + koff + seg * 8;
    const bf16_t* pB0 = Wt + (size_t)rB0 * K + koff + seg * 8;
    const bf16_t* pB1 = Wt + (size_t)rB1 * K + koff + seg * 8;
    const int lofs0 = wave * 512;          // within a buffer
    const int lofs1 = 2048 + wave * 512;

    auto stage = [&](int kt2, int buf) {   // 4 loads/wave, FIFO group
        const int kb = kt2 << 5;
        gld_lds16(pA0 + kb, As[buf] + lofs0);
        gld_lds16(pA1 + kb, As[buf] + lofs1);
        gld_lds16(pB0 + kb, Bs[buf] + lofs0);
        gld_lds16(pB1 + kb, Bs[buf] + lofs1);
    };

    const int nkt = klen >> 5;   // >= 24 for all call sites (>= 48 for split)
    // prologue: stage K-tiles 0 and 1 (8 loads/wave in flight)
    stage(0, 0);
    stage(1, 1);

    for (int kt = 0; kt < nkt; ++kt) {
        const int cur = kt & 1;
        // wait: tile kt's 4 loads (oldest) done; tile kt+1's stay in flight
        if (kt + 1 < nkt) asm volatile("s_waitcnt vmcnt(4)" ::: "memory");
        else              asm volatile("s_waitcnt vmcnt(0)" ::: "memory");
        __builtin_amdgcn_s_barrier();   // all waves' tile-kt loads landed

        bf16x8 af[4], bfr[4];
#pragma unroll
        for (int i = 0; i < 4; ++i)
            af[i] = *reinterpret_cast<const bf16x8*>(As[cur] + (wm * 64 + i * 16 + l16) * 32 + quad * 8);
#pragma unroll
        for (int j = 0; j < 4; ++j)
            bfr[j] = *reinterpret_cast<const bf16x8*>(Bs[cur] + (wn * 64 + j * 16 + l16) * 32 + quad * 8);

        asm volatile("s_waitcnt lgkmcnt(0)" ::: "memory");  // my LDS reads done
        __builtin_amdgcn_sched_barrier(0);
        __builtin_amdgcn_s_barrier();   // everyone's reads done -> buf reusable

        if (kt + 2 < nkt) stage(kt + 2, cur);   // overwrite buf[cur] for kt+2

#pragma unroll
        for (int i = 0; i < 4; ++i)
#pragma unroll
            for (int j = 0; j < 4; ++j)
                acc[i][j] = mfma16(af[i], bfr[j], acc[i][j]);
    }

    // epilogue: C/D layout col=lane&15, row=quad*4+reg
    const bool addb = bias && (!AT || blockIdx.z == 0);
#pragma unroll
    for (int j = 0; j < 4; ++j) {
        int c = n0 + wn * 64 + j * 16 + l16;
        if (c >= N) continue;
        float bj = addb ? bias[c] : 0.f;
#pragma unroll
        for (int i = 0; i < 4; ++i) {
#pragma unroll
            for (int r = 0; r < 4; ++r) {
                int mr = m0 + wm * 64 + i * 16 + quad * 4 + r;
                if (mr >= M) continue;
                float v = acc[i][j][r] + bj;
                int orow = SC ? rowidx[mr] : mr;
                size_t off = (size_t)orow * ldc + c;
                if (MODE == EP_BF16) {
                    ((bf16_t*)Cout)[off] = (bf16_t)v;
                } else if (MODE == EP_GELU) {
                    float g = 0.5f * v * (1.f + erff(v * 0.70710678118f));
                    ((bf16_t*)Cout)[off] = (bf16_t)g;
                } else if (MODE == EP_F32) {
                    ((float*)Cout)[off] = v;
                } else { // EP_RES
                    if (AT) atomicAdd(&resid[off], v);
                    else    resid[off] += v;
                }
            }
        }
    }
}

// ------------------------------ LayerNorm ----------------------------------
DI float block_reduce_sum(float val, float* sh) {
#pragma unroll
    for (int off = 32; off; off >>= 1) val += __shfl_down(val, off, 64);
    __syncthreads();
    if ((threadIdx.x & 63) == 0) sh[threadIdx.x >> 6] = val;
    __syncthreads();
    return sh[0] + sh[1] + sh[2] + sh[3];
}

// in row = blockIdx.x * row_mul (fp32); OUT = bf16 or fp32
template<typename OUT>
__global__ __launch_bounds__(256)
void ln_kernel(const float* __restrict__ X, const float* __restrict__ g,
               const float* __restrict__ bta, OUT* __restrict__ H, int row_mul)
{
    __shared__ float sh[4];
    const int t = threadIdx.x;
    const float* xr = X + (size_t)blockIdx.x * row_mul * DMODEL;
    float v[3];
#pragma unroll
    for (int i = 0; i < 3; ++i) v[i] = xr[t + i * 256];
    float s = v[0] + v[1] + v[2];
    s = block_reduce_sum(s, sh);
    float mu = s * (1.f / DMODEL);
    float q = 0.f;
#pragma unroll
    for (int i = 0; i < 3; ++i) { float d = v[i] - mu; q += d * d; }
    q = block_reduce_sum(q, sh);
    float rstd = rsqrtf(q * (1.f / DMODEL) + LNEPS);
    OUT* hr = H + (size_t)blockIdx.x * DMODEL;
#pragma unroll
    for (int i = 0; i < 3; ++i) {
        int c = t + i * 256;
        hr[c] = (OUT)((v[i] - mu) * rstd * g[c] + bta[c]);
    }
}

// ------------------------------ Attention ----------------------------------
__global__ __launch_bounds__(256)
void attn_kernel(const bf16_t* __restrict__ qkv,   // [B][197][3][768]
                 const float* __restrict__ addmask, // [B][197] or null
                 bf16_t* __restrict__ outp)          // [B][197][768]
{
    constexpr int KP = 232;  // padded key stride (>=224, 16B-multiple rows)
    __shared__ __align__(16) bf16_t Vt[64 * KP];       // Vt[hd][key]
    __shared__ __align__(16) bf16_t Ps[4][16 * KP];    // per-wave P[q][key]
    const int b = blockIdx.z, h = blockIdx.y, qt = blockIdx.x;
    const int tid = threadIdx.x, wave = tid >> 6, lane = tid & 63;
    const int quad = lane >> 4, l16 = lane & 15;

    // stage V^T (zero-padded keys 197..223)
    {
        int d = tid & 63, ng = tid >> 6;
        for (int n = ng; n < 224; n += 4) {
            bf16_t v = (bf16_t)0.f;
            if (n < 197)
                v = qkv[(((size_t)b * NTOK + n) * 3 + 2) * DMODEL + h * HDIM + d];
            Vt[d * KP + n] = v;
        }
    }
    __syncthreads();

    // Q fragments straight from global (A-op: m=lane&15, k=quad*8+j)
    const int qbase = qt * 64 + wave * 16;
    const int qrow = qbase + l16;
    const int qc = qrow < 196 ? qrow : 196;
    bf16x8 aq[2];
#pragma unroll
    for (int t = 0; t < 2; ++t)
        aq[t] = *reinterpret_cast<const bf16x8*>(
            qkv + (((size_t)b * NTOK + qc) * 3 + 0) * DMODEL + h * HDIM + t * 32 + quad * 8);

    // scores: 13 key-tiles of 16
    float sreg[13][4];
#pragma unroll
    for (int kt = 0; kt < 13; ++kt) {
        int key = kt * 16 + l16;
        int kc = key < 196 ? key : 196;
        const bf16_t* kb = qkv + (((size_t)b * NTOK + kc) * 3 + 1) * DMODEL + h * HDIM;
        bf16x8 kf0 = *reinterpret_cast<const bf16x8*>(kb + quad * 8);
        bf16x8 kf1 = *reinterpret_cast<const bf16x8*>(kb + 32 + quad * 8);
        f32x4 s = {0.f, 0.f, 0.f, 0.f};
        s = mfma16(aq[0], kf0, s);
        s = mfma16(aq[1], kf1, s);
        float am = addmask ? addmask[b * NTOK + kc] : 0.f;
        bool kvalid = key < 197;
#pragma unroll
        for (int r = 0; r < 4; ++r)
            sreg[kt][r] = kvalid ? (s[r] * ATT_SCALE + am) : -1e30f;
    }

    // softmax rows (row = quad*4+r, spread over the 16 lanes of the quad)
    float psum[4];
#pragma unroll
    for (int r = 0; r < 4; ++r) {
        float mx = -1e30f;
#pragma unroll
        for (int kt = 0; kt < 13; ++kt) mx = fmaxf(mx, sreg[kt][r]);
#pragma unroll
        for (int d = 1; d < 16; d <<= 1) mx = fmaxf(mx, __shfl_xor(mx, d, 64));
        float sum = 0.f;
#pragma unroll
        for (int kt = 0; kt < 13; ++kt) {
            float p = expf(sreg[kt][r] - mx);
            sreg[kt][r] = p;
            sum += p;
        }
#pragma unroll
        for (int d = 1; d < 16; d <<= 1) sum += __shfl_xor(sum, d, 64);
        psum[r] = sum;
    }

    // write P to LDS (C-layout -> A-layout transform), zero-pad cols 208..223
#pragma unroll
    for (int kt = 0; kt < 13; ++kt)
#pragma unroll
        for (int r = 0; r < 4; ++r)
            Ps[wave][(quad * 4 + r) * KP + kt * 16 + l16] = (bf16_t)sreg[kt][r];
    {
        int rr = lane & 15, c0 = 208 + (lane >> 4) * 4;
#pragma unroll
        for (int i = 0; i < 4; ++i) Ps[wave][rr * KP + c0 + i] = (bf16_t)0.f;
    }
    __syncthreads();   // P-write -> PV-read ordering

    // O = P @ V  (7 K-steps of 32 keys)
    f32x4 o[4];
#pragma unroll
    for (int j = 0; j < 4; ++j) o[j] = (f32x4){0.f, 0.f, 0.f, 0.f};
#pragma unroll
    for (int ks = 0; ks < 7; ++ks) {
        bf16x8 ap = *reinterpret_cast<const bf16x8*>(&Ps[wave][l16 * KP + ks * 32 + quad * 8]);
#pragma unroll
        for (int j = 0; j < 4; ++j) {
            bf16x8 vf = *reinterpret_cast<const bf16x8*>(&Vt[(j * 16 + l16) * KP + ks * 32 + quad * 8]);
            o[j] = mfma16(ap, vf, o[j]);
        }
    }

    // normalize + store
#pragma unroll
    for (int r = 0; r < 4; ++r) {
        int q = qbase + quad * 4 + r;
        if (q < 197) {
            float rs = 1.f / fmaxf(psum[r], 1e-20f);
#pragma unroll
            for (int j = 0; j < 4; ++j)
                outp[((size_t)b * NTOK + q) * DMODEL + h * HDIM + j * 16 + l16] =
                    (bf16_t)(o[j][r] * rs);
        }
    }
}

// --------------------------- small kernels ---------------------------------
__global__ __launch_bounds__(256)
void transpose_f32(const float* __restrict__ src, bf16_t* __restrict__ dst, int K, int N)
{
    __shared__ bf16_t tile[64][65];
    const size_t ls = (size_t)K * N * blockIdx.z;
    int k0 = blockIdx.y * 64, n0 = blockIdx.x * 64;
    int c = threadIdx.x & 63, r0 = threadIdx.x >> 6;
#pragma unroll
    for (int i = 0; i < 16; ++i) {
        int r = r0 + i * 4;
        tile[r][c] = (k0 + r < K && n0 + c < N)
                   ? (bf16_t)src[ls + (size_t)(k0 + r) * N + n0 + c] : (bf16_t)0.f;
    }
    __syncthreads();
#pragma unroll
    for (int i = 0; i < 16; ++i) {
        int r = r0 + i * 4;  // n-dim
        if (n0 + r < N && k0 + c < K) dst[ls + (size_t)(n0 + r) * K + k0 + c] = tile[c][r];
    }
}

__global__ void cvt_f32_bf16(const float* __restrict__ src, bf16_t* __restrict__ dst, int n)
{
    int i = blockIdx.x * 256 + threadIdx.x;
    if (i < n) dst[i] = (bf16_t)src[i];
}

__global__ void im2col_kernel(const float* __restrict__ img, bf16_t* __restrict__ Ap)
{
    int idx = blockIdx.x * 256 + threadIdx.x;
    if (idx >= PROWS * 768) return;
    int col = idx % 768, row = idx / 768;
    int b = row / 196, t = row % 196;
    int gi = t / 14, gj = t % 14;
    int c = col >> 8, rr = col & 255, p = rr >> 4, q = rr & 15;
    Ap[idx] = (bf16_t)img[(((size_t)b * 3 + c) * 224 + gi * 16 + p) * 224 + gj * 16 + q];
}

__global__ void assemble_x(const float* __restrict__ patch, const float* __restrict__ cls,
                           const float* __restrict__ pos, float* __restrict__ X)
{
    int idx = blockIdx.x * 256 + threadIdx.x;
    if (idx >= MROWS * DMODEL) return;
    int d = idx % DMODEL, rest = idx / DMODEL;
    int n = rest % NTOK, b = rest / NTOK;
    float v;
    if (n == 0) v = cls[d] + pos[d];
    else        v = patch[((size_t)b * 196 + (n - 1)) * DMODEL + d] + pos[(size_t)n * DMODEL + d];
    X[idx] = v;
}

// ---- gate path (fp32 end-to-end; top-k ranks must match np exactly) -------
// Fused: logits[m] = dot(gelu(A[m]@W1 + b1), w2) + b2, all fp32.
__global__ __launch_bounds__(256)
void gate_fused_f32(const float* __restrict__ A, const float* __restrict__ W1,
                    const float* __restrict__ b1, const float* __restrict__ w2,
                    const float* __restrict__ b2, float* __restrict__ logits)
{
    __shared__ __align__(16) float As[16][64];
    __shared__ __align__(16) float Ws[64][128];
    const int tid = threadIdx.x;
    const int m0 = blockIdx.x * 16;
    const int tx = tid & 31;       // col group: cols tx*4..tx*4+3
    const int rg = tid >> 5;       // 0..7 -> rows rg*2, rg*2+1
    f32x4 acc0 = {0.f, 0.f, 0.f, 0.f};
    f32x4 acc1 = {0.f, 0.f, 0.f, 0.f};
    for (int k0 = 0; k0 < 768; k0 += 64) {
        __syncthreads();
        {   // stage A-tile: 1024 floats = 256 float4 (1/thread)
            int idx = tid * 4;
            int r = idx >> 6, c = idx & 63;
            *reinterpret_cast<f32x4*>(&As[r][c]) =
                *reinterpret_cast<const f32x4*>(&A[(size_t)(m0 + r) * 768 + k0 + c]);
        }
#pragma unroll
        for (int i = 0; i < 8; ++i) {  // stage W-tile: 8192 floats = 8 float4/thread
            int idx = (tid + i * 256) * 4;
            int r = idx >> 7, c = idx & 127;
            *reinterpret_cast<f32x4*>(&Ws[r][c]) =
                *reinterpret_cast<const f32x4*>(&W1[(size_t)(k0 + r) * 128 + c]);
        }
        __syncthreads();
#pragma unroll
        for (int kk = 0; kk < 64; ++kk) {
            float a0 = As[rg * 2 + 0][kk];   // broadcast (2 addrs/wave: free)
            float a1 = As[rg * 2 + 1][kk];
            f32x4 w = *reinterpret_cast<const f32x4*>(&Ws[kk][tx * 4]);  // b128, conflict-free
#pragma unroll
            for (int j = 0; j < 4; ++j) {
                acc0[j] += a0 * w[j];
                acc1[j] += a1 * w[j];
            }
        }
    }
    // epilogue: bias + gelu + dot(w2), reduce across the 32 tx lanes
    float s0 = 0.f, s1 = 0.f;
#pragma unroll
    for (int j = 0; j < 4; ++j) {
        int c = tx * 4 + j;
        float bj = b1[c], wj = w2[c];
        float v0 = acc0[j] + bj;
        float v1 = acc1[j] + bj;
        s0 += 0.5f * v0 * (1.f + erff(v0 * 0.70710678118f)) * wj;
        s1 += 0.5f * v1 * (1.f + erff(v1 * 0.70710678118f)) * wj;
    }
#pragma unroll
    for (int d = 1; d < 32; d <<= 1) {
        s0 += __shfl_xor(s0, d, 64);
        s1 += __shfl_xor(s1, d, 64);
    }
    if (tx == 0) {
        logits[m0 + rg * 2 + 0] = s0 + b2[0];
        logits[m0 + rg * 2 + 1] = s1 + b2[0];
    }
}

// exact top-118 of logits[b,1:197] by rank counting (lax.top_k tie-break:
// lower index). Also emits rank-ordered compaction rowidx[b*119 + p]:
// p=0 -> cls row, p=1+rank -> selected patch rows (ranks unique).
__global__ __launch_bounds__(256)
void topk_kernel(const float* __restrict__ logits, float* __restrict__ maskm,
                 float* __restrict__ addm, int* __restrict__ rowidx)
{
    __shared__ float ls[196];
    int b = blockIdx.x, t = threadIdx.x;
    if (t < 196) ls[t] = logits[b * NTOK + 1 + t];
    __syncthreads();
    if (t < 196) {
        float li = ls[t];
        int cnt = 0;
        for (int j = 0; j < 196; ++j) {
            float lj = ls[j];
            cnt += (lj > li) || (lj == li && j < t);
        }
        bool sel = cnt < KTOP;
        maskm[b * NTOK + 1 + t] = sel ? 1.f : 0.f;
        addm[b * NTOK + 1 + t]  = sel ? 0.f : LOGEPS;
        if (sel) rowidx[b * NSEL + 1 + cnt] = b * NTOK + 1 + t;
    }
    if (t == 0) { maskm[b * NTOK] = 1.f; addm[b * NTOK] = 0.f; rowidx[b * NSEL] = b * NTOK; }
}

__global__ void fill_sentinel(float* out, int n)
{
    int i = blockIdx.x * 256 + threadIdx.x;
    if (i < n) out[i] = 12345.0f;
}

// ------------------------------- host --------------------------------------
static void launch_gemm(int mode, const bf16_t* A, const bf16_t* Wt, const float* bias,
                        void* C, float* resid,
                        int M, int N, int K, int ldc, hipStream_t s)
{
    dim3 grid((N + 127) / 128, (M + 127) / 128);
    dim3 blk(256);
    switch (mode) {
    case EP_BF16: gemm_bf16<EP_BF16, false, false, false><<<grid, blk, 0, s>>>(A, Wt, bias, C, resid, nullptr, M, N, K, ldc, K); break;
    case EP_GELU: gemm_bf16<EP_GELU, false, false, false><<<grid, blk, 0, s>>>(A, Wt, bias, C, resid, nullptr, M, N, K, ldc, K); break;
    case EP_RES:  gemm_bf16<EP_RES,  false, false, false><<<grid, blk, 0, s>>>(A, Wt, bias, C, resid, nullptr, M, N, K, ldc, K); break;
    case EP_F32:  gemm_bf16<EP_F32,  false, false, false><<<grid, blk, 0, s>>>(A, Wt, bias, C, resid, nullptr, M, N, K, ldc, K); break;
    }
}

extern "C" void kernel_launch(void* const* d_in, const int* in_sizes, int n_in,
                              void* d_out, int out_size, void* d_ws, size_t ws_size,
                              hipStream_t stream)
{
    (void)in_sizes; (void)n_in;
    const float* images   = (const float*)d_in[0];
    const float* patch_w  = (const float*)d_in[1];
    const float* patch_b  = (const float*)d_in[2];
    const float* cls_tok  = (const float*)d_in[3];
    const float* pos_emb  = (const float*)d_in[4];
    const float* w_ln1_g  = (const float*)d_in[5];
    const float* w_ln1_b  = (const float*)d_in[6];
    const float* w_qkv_w  = (const float*)d_in[7];
    const float* w_qkv_b  = (const float*)d_in[8];
    const float* w_proj_w = (const float*)d_in[9];
    const float* w_proj_b = (const float*)d_in[10];
    const float* w_ln2_g  = (const float*)d_in[11];
    const float* w_ln2_b  = (const float*)d_in[12];
    const float* w_fc1_w  = (const float*)d_in[13];
    const float* w_fc1_b  = (const float*)d_in[14];
    const float* w_fc2_w  = (const float*)d_in[15];
    const float* w_fc2_b  = (const float*)d_in[16];
    const float* d_ln1_g  = (const float*)d_in[17];
    const float* d_ln1_b  = (const float*)d_in[18];
    const float* d_qkv_w  = (const float*)d_in[19];
    const float* d_qkv_b  = (const float*)d_in[20];
    const float* d_proj_w = (const float*)d_in[21];
    const float* d_proj_b = (const float*)d_in[22];
    const float* d_ln2_g  = (const float*)d_in[23];
    const float* d_ln2_b  = (const float*)d_in[24];
    const float* d_fc1_w  = (const float*)d_in[25];
    const float* d_fc1_b  = (const float*)d_in[26];
    const float* d_fc2_w  = (const float*)d_in[27];
    const float* d_fc2_b  = (const float*)d_in[28];
    const float* d_gln_g  = (const float*)d_in[29];
    const float* d_gln_b  = (const float*)d_in[30];
    const float* d_gw1    = (const float*)d_in[31];
    const float* d_gb1    = (const float*)d_in[32];
    const float* d_gw2    = (const float*)d_in[33];
    const float* d_gb2    = (const float*)d_in[34];
    const float* norm_g   = (const float*)d_in[35];
    const float* norm_b   = (const float*)d_in[36];
    const float* head_w   = (const float*)d_in[37];
    const float* head_b   = (const float*)d_in[38];

    // workspace layout
    char* wp = (char*)d_ws;
    auto alloc = [&](size_t bytes) -> char* {
        char* p = wp; wp += (bytes + 255) & ~(size_t)255; return p;
    };
    bf16_t* wtqkv  = (bf16_t*)alloc((size_t)NLAYER * 2304 * 768 * 2);
    bf16_t* wtproj = (bf16_t*)alloc((size_t)NLAYER * 768 * 768 * 2);
    bf16_t* wtfc1  = (bf16_t*)alloc((size_t)NLAYER * 3072 * 768 * 2);
    bf16_t* wtfc2  = (bf16_t*)alloc((size_t)NLAYER * 768 * 3072 * 2);
    bf16_t* wthead = (bf16_t*)alloc((size_t)1024 * 768 * 2);
    bf16_t* pwbf   = (bf16_t*)alloc((size_t)768 * 768 * 2);
    float*  x      = (float*)alloc((size_t)MROWS * DMODEL * 4);
    bf16_t* h      = (bf16_t*)alloc((size_t)MROWS * DMODEL * 2);
    float*  hgate  = (float*)alloc((size_t)MROWS * DMODEL * 4);
    bf16_t* hcls   = (bf16_t*)alloc((size_t)NB * DMODEL * 2);
    bf16_t* qkvb   = (bf16_t*)alloc((size_t)MROWS * 2304 * 2);
    bf16_t* attno  = (bf16_t*)alloc((size_t)MROWS * DMODEL * 2);
    bf16_t* hid    = (bf16_t*)alloc((size_t)MROWS * HIDN * 2);
    float*  logits = (float*)alloc((size_t)MROWS * 4);
    float*  maskm  = (float*)alloc((size_t)MROWS * 4);
    float*  addm   = (float*)alloc((size_t)MROWS * 4);
    int*    rowidx = (int*)alloc((size_t)MROWSC * 4);
    size_t used = (size_t)(wp - (char*)d_ws);
    if (used > ws_size) {  // diagnostic: distinctive absmax if ws is too small
        fill_sentinel<<<(out_size + 255) / 256, 256, 0, stream>>>((float*)d_out, out_size);
        return;
    }
    // patch scratch aliases hid (patch phase precedes any MLP use)
    bf16_t* Ap = hid;                                    // [6272][768] bf16
    float* patchout = (float*)((char*)hid + (size_t)PROWS * 768 * 2); // [6272][768] f32

    // ---- weight pre-transpose ([K][N] -> [N][K] bf16) ----
    transpose_f32<<<dim3(36, 12, 2),  256, 0, stream>>>(w_qkv_w,  wtqkv,                      768, 2304);
    transpose_f32<<<dim3(36, 12, 10), 256, 0, stream>>>(d_qkv_w,  wtqkv + (size_t)2*2304*768, 768, 2304);
    transpose_f32<<<dim3(12, 12, 2),  256, 0, stream>>>(w_proj_w, wtproj,                     768, 768);
    transpose_f32<<<dim3(12, 12, 10), 256, 0, stream>>>(d_proj_w, wtproj + (size_t)2*768*768, 768, 768);
    transpose_f32<<<dim3(48, 12, 2),  256, 0, stream>>>(w_fc1_w,  wtfc1,                      768, 3072);
    transpose_f32<<<dim3(48, 12, 10), 256, 0, stream>>>(d_fc1_w,  wtfc1 + (size_t)2*3072*768, 768, 3072);
    transpose_f32<<<dim3(12, 48, 2),  256, 0, stream>>>(w_fc2_w,  wtfc2,                      3072, 768);
    transpose_f32<<<dim3(12, 48, 10), 256, 0, stream>>>(d_fc2_w,  wtfc2 + (size_t)2*768*3072, 3072, 768);
    transpose_f32<<<dim3(16, 12, 1),  256, 0, stream>>>(head_w,   wthead,                     768, 1000);
    cvt_f32_bf16<<<(768 * 768 + 255) / 256, 256, 0, stream>>>(patch_w, pwbf, 768 * 768);

    // ---- patch embed + assemble ----
    im2col_kernel<<<(PROWS * 768 + 255) / 256, 256, 0, stream>>>(images, Ap);
    launch_gemm(EP_F32, Ap, pwbf, patch_b, patchout, nullptr,
                PROWS, 768, 768, 768, stream);
    assemble_x<<<(MROWS * DMODEL + 255) / 256, 256, 0, stream>>>(patchout, cls_tok, pos_emb, x);

    // ---- transformer layers ----
    for (int L = 0; L < NLAYER; ++L) {
        bool warm = (L < 2);
        int li = warm ? L : (L - 2);
        const float* ln1g = warm ? w_ln1_g + li*768 : d_ln1_g + li*768;
        const float* ln1b = warm ? w_ln1_b + li*768 : d_ln1_b + li*768;
        const float* ln2g = warm ? w_ln2_g + li*768 : d_ln2_g + li*768;
        const float* ln2b = warm ? w_ln2_b + li*768 : d_ln2_b + li*768;
        const float* qkvbias  = warm ? w_qkv_b + li*2304 : d_qkv_b + li*2304;
        const float* projbias = warm ? w_proj_b + li*768 : d_proj_b + li*768;
        const float* fc1bias  = warm ? w_fc1_b + (size_t)li*3072 : d_fc1_b + (size_t)li*3072;
        const float* fc2bias  = warm ? w_fc2_b + li*768 : d_fc2_b + li*768;
        const bf16_t* Wq = wtqkv + (size_t)L * 2304 * 768;
        const bf16_t* Wp = wtproj + (size_t)L * 768 * 768;
        const bf16_t* W1 = wtfc1 + (size_t)L * 3072 * 768;
        const bf16_t* W2 = wtfc2 + (size_t)L * 768 * 3072;

        if (!warm) {
            // gate: LN -> fused fc1+gelu+dot -> top-118 mask + compaction idx
            ln_kernel<float><<<MROWS, 256, 0, stream>>>(x, d_gln_g + li*768, d_gln_b + li*768, hgate, 1);
            gate_fused_f32<<<MROWS / 16, 256, 0, stream>>>(
                hgate, d_gw1 + (size_t)li*768*128, d_gb1 + li*128,
                d_gw2 + (size_t)li*128, d_gb2 + li, logits);
            topk_kernel<<<NB, 256, 0, stream>>>(logits, maskm, addm, rowidx);
        }
        // attention (all rows)
        ln_kernel<bf16_t><<<MROWS, 256, 0, stream>>>(x, ln1g, ln1b, h, 1);
        launch_gemm(EP_BF16, h, Wq, qkvbias, qkvb, nullptr,
                    MROWS, 2304, 768, 2304, stream);
        attn_kernel<<<dim3(4, NHEAD, NB), 256, 0, stream>>>(qkvb, warm ? nullptr : addm, attno);
        launch_gemm(EP_RES, attno, Wp, projbias, nullptr, x,
                    MROWS, 768, 768, 768, stream);
        // MLP
        ln_kernel<bf16_t><<<MROWS, 256, 0, stream>>>(x, ln2g, ln2b, h, 1);
        if (warm) {
            launch_gemm(EP_GELU, h, W1, fc1bias, hid, nullptr,
                        MROWS, 3072, 768, 3072, stream);
            launch_gemm(EP_RES, hid, W2, fc2bias, nullptr, x,
                        MROWS, 768, 3072, 768, stream);
        } else {
            // compacted MLP: only the 119 selected rows/batch (x += v*m)
            dim3 g1(24, (MROWSC + 127) / 128);           // fc1: gather A rows
            gemm_bf16<EP_GELU, true, false, false><<<g1, 256, 0, stream>>>(
                h, W1, fc1bias, hid, nullptr, rowidx, MROWSC, 3072, 768, 3072, 768);
            dim3 g2(6, (MROWSC + 127) / 128, 2);         // fc2: split-K=2, scatter+atomic
            gemm_bf16<EP_RES, false, true, true><<<g2, 256, 0, stream>>>(
                hid, W2, fc2bias, nullptr, x, rowidx, MROWSC, 768, 3072, 768, 1536);
        }
    }

    // ---- final LN (cls rows only) + head -> fp32 d_out ----
    ln_kernel<bf16_t><<<NB, 256, 0, stream>>>(x, norm_g, norm_b, hcls, NTOK);
    launch_gemm(EP_F32, hcls, wthead, head_b, d_out, nullptr,
                NB, 1000, 768, 1000, stream);
}